// Round 3
// baseline (472.395 us; speedup 1.0000x reference)
//
#include <hip/hip_runtime.h>
#include <stdint.h>

typedef unsigned short u16;
typedef __bf16 bf16x8 __attribute__((ext_vector_type(8)));
typedef float f32x4 __attribute__((ext_vector_type(4)));

__device__ __forceinline__ u16 f2bf(float f){
  unsigned u = __float_as_uint(f);
  unsigned r = (u + 0x7FFFu + ((u>>16)&1u)) >> 16;
  return (u16)r;
}

// ---------------------------------------------------------------------------
// Fused transpose of all weights fp32 -> bf16 [n][k] (BT) layout.
// W1 additionally gets column-interleaved: gemm col 2j = x-part col j,
// col 2j+1 = gate col j (orig col 512+j), enabling fused SiLU-GLU epilogue.
// Blocks: 0-63 Wq, 64-127 Wk, 128-191 Wv, 192-255 Wo, 256-511 W1, 512-639 W2
// ---------------------------------------------------------------------------
__global__ void transpose_all(const float* __restrict__ Wq, const float* __restrict__ Wk,
                              const float* __restrict__ Wv, const float* __restrict__ Wo,
                              const float* __restrict__ W1, const float* __restrict__ W2,
                              u16* __restrict__ wqkvT, u16* __restrict__ woT,
                              u16* __restrict__ w1T, u16* __restrict__ w2T)
{
  __shared__ u16 tile[32][33];
  int bid = blockIdx.x;
  const float* in; u16* out; int K, N, t2; bool glu = false;
  if (bid < 64)       { in = Wq; out = wqkvT;           K = 256; N = 256;  t2 = bid; }
  else if (bid < 128) { in = Wk; out = wqkvT + 65536;   K = 256; N = 256;  t2 = bid - 64; }
  else if (bid < 192) { in = Wv; out = wqkvT + 131072;  K = 256; N = 256;  t2 = bid - 128; }
  else if (bid < 256) { in = Wo; out = woT;             K = 256; N = 256;  t2 = bid - 192; }
  else if (bid < 512) { in = W1; out = w1T;             K = 256; N = 1024; t2 = bid - 256; glu = true; }
  else                { in = W2; out = w2T;             K = 512; N = 256;  t2 = bid - 512; }
  int ntn = N >> 5;
  int k0 = (t2 / ntn) * 32, n0 = (t2 % ntn) * 32;
  int t = threadIdx.x;
  #pragma unroll
  for (int p = 0; p < 4; ++p) {
    int u = t + p * 256; int r = u >> 5, c = u & 31;
    tile[r][c] = f2bf(in[(size_t)(k0 + r) * N + n0 + c]);
  }
  __syncthreads();
  #pragma unroll
  for (int p = 0; p < 4; ++p) {
    int u = t + p * 256; int r = u >> 5, c = u & 31;
    int q = n0 + r;
    int row = glu ? (q < 512 ? 2 * q : 2 * (q - 512) + 1) : q;
    out[(size_t)row * K + k0 + c] = tile[c][r];
  }
}

// ---------------------------------------------------------------------------
// Generic 128x128-tile bf16 GEMM: C = A(MxK) * BT(NxK)^T, with epilogue modes.
// A is fp32 (converted during LDS staging) when AF32=1, else bf16.
// BT is always pre-converted bf16.
// ---------------------------------------------------------------------------
enum { MODE_QKV = 0, MODE_Y_RES = 1, MODE_GLU = 2 };

template<int MODE, int AF32>
__launch_bounds__(256, 2)
__global__ void gemm_kernel(const void* __restrict__ Ap, const u16* __restrict__ BT,
                            int M, int N, int K,
                            const float* __restrict__ bias, const float* __restrict__ res,
                            float* __restrict__ outF, u16* __restrict__ outB)
{
  const float* Af = (const float*)Ap;
  const u16*   Ab = (const u16*)Ap;
  __shared__ u16 As[128 * 40];
  __shared__ u16 Bs[128 * 40];
  const int t = threadIdx.x;
  const int m0 = blockIdx.x * 128;
  const int n0 = blockIdx.y * 128;
  const int lane = t & 63;
  const int w = t >> 6;
  const int wm = (w >> 1) * 64;
  const int wn = (w & 1) * 64;
  const int fr = lane & 15;
  const int fg = lane >> 4;

  f32x4 acc[4][4];
  #pragma unroll
  for (int i = 0; i < 4; ++i)
    #pragma unroll
    for (int j = 0; j < 4; ++j)
      acc[i][j] = (f32x4){0.f, 0.f, 0.f, 0.f};

  for (int k0 = 0; k0 < K; k0 += 32) {
    __syncthreads();
    #pragma unroll
    for (int p = 0; p < 2; ++p) {
      int u = t + p * 256;
      int row = u >> 2, cb = u & 3;
      if (AF32) {
        const float* pa = Af + (size_t)(m0 + row) * K + k0 + cb * 8;
        float4 a0 = *(const float4*)pa;
        float4 a1 = *(const float4*)(pa + 4);
        union { u16 u[8]; uint4 v; } pk;
        pk.u[0] = f2bf(a0.x); pk.u[1] = f2bf(a0.y); pk.u[2] = f2bf(a0.z); pk.u[3] = f2bf(a0.w);
        pk.u[4] = f2bf(a1.x); pk.u[5] = f2bf(a1.y); pk.u[6] = f2bf(a1.z); pk.u[7] = f2bf(a1.w);
        *(uint4*)(As + row * 40 + cb * 8) = pk.v;
      } else {
        float4 va = *(const float4*)(Ab + (size_t)(m0 + row) * K + k0 + cb * 8);
        *(float4*)(As + row * 40 + cb * 8) = va;
      }
      float4 vb = *(const float4*)(BT + (size_t)(n0 + row) * K + k0 + cb * 8);
      *(float4*)(Bs + row * 40 + cb * 8) = vb;
    }
    __syncthreads();
    bf16x8 af[4], bfr[4];
    #pragma unroll
    for (int i = 0; i < 4; ++i) af[i]  = *(const bf16x8*)(As + (wm + i * 16 + fr) * 40 + fg * 8);
    #pragma unroll
    for (int j = 0; j < 4; ++j) bfr[j] = *(const bf16x8*)(Bs + (wn + j * 16 + fr) * 40 + fg * 8);
    #pragma unroll
    for (int i = 0; i < 4; ++i)
      #pragma unroll
      for (int j = 0; j < 4; ++j)
        acc[i][j] = __builtin_amdgcn_mfma_f32_16x16x32_bf16(af[i], bfr[j], acc[i][j], 0, 0, 0);
  }

  #pragma unroll
  for (int j = 0; j < 4; ++j) {
    int col = n0 + wn + j * 16 + fr;
    float bv = 0.f;
    if (MODE == MODE_Y_RES) bv = bias[col];
    if (MODE == MODE_GLU)   bv = bias[(col >> 1) + ((col & 1) << 9)];
    #pragma unroll
    for (int i = 0; i < 4; ++i) {
      #pragma unroll
      for (int r = 0; r < 4; ++r) {
        int row = m0 + wm + i * 16 + fg * 4 + r;
        float v = acc[i][j][r] + bv;
        if (MODE == MODE_QKV) {
          int which = col >> 8, h = (col >> 4) & 15, d = col & 15;
          int b = row >> 10, ns = row & 1023;
          outB[(size_t)which * 4194304 + (((size_t)(b * 16 + h) * 1024 + ns) * 16 + d)] = f2bf(v);
        } else if (MODE == MODE_Y_RES) {
          size_t idx = (size_t)row * N + col;
          outF[idx] = v + res[idx];
        } else { // MODE_GLU: even col = x-part, odd col = gate; pairs differ in lane bit 0
          float partner = __shfl_xor(v, 1);
          if ((fr & 1) == 0) {
            float g = partner / (1.f + __expf(-partner));  // silu(gate)
            outB[(size_t)row * 512 + (col >> 1)] = f2bf(g * v);
          }
        }
      }
    }
  }
}

// ---------------------------------------------------------------------------
// Attention: one block per (b,h). K + V^T staged in LDS; flash online softmax
// in exp2 domain; P round-trips LDS (C-layout -> A-layout) per wave.
// Q/K/V arrive as bf16 [b][h][n][d] from the QKV GEMM scatter.
// ---------------------------------------------------------------------------
#define SCALE_L2 0.360673760222241f   /* (1/sqrt(16)) * log2(e) */

__launch_bounds__(512, 1)
__global__ void attn_kernel(const u16* __restrict__ Q, const u16* __restrict__ Kg,
                            const u16* __restrict__ Vg, u16* __restrict__ outp)
{
  __shared__ u16 Ks[1024 * 24];    // [key][d] padded 16->24
  __shared__ u16 Vt[16 * 1032];    // [d][key] padded 1024->1032
  __shared__ u16 Pb[8 * 16 * 40];  // per-wave P buffer [16][40]
  const int t = threadIdx.x;
  const int bh = blockIdx.x;
  const int b = bh >> 4, h = bh & 15;
  const size_t base = (size_t)bh * (1024 * 16);

  for (int u = t; u < 2048; u += 512) {
    int row = u >> 1, half = u & 1;
    float4 v = *(const float4*)(Kg + base + row * 16 + half * 8);
    *(float4*)(Ks + row * 24 + half * 8) = v;
  }
  for (int u = t; u < 2048; u += 512) {
    int row = u >> 1, half = u & 1;
    const u16* src = Vg + base + row * 16 + half * 8;
    #pragma unroll
    for (int j = 0; j < 8; ++j) Vt[(half * 8 + j) * 1032 + row] = src[j];
  }
  __syncthreads();

  const int w = t >> 6, lane = t & 63;
  const int fr = lane & 15, fg = lane >> 4;
  u16* Pw = Pb + w * (16 * 40);
  const f32x4 zero4 = (f32x4){0.f, 0.f, 0.f, 0.f};

  for (int qt = w; qt < 64; qt += 8) {
    const int q0 = qt * 16;
    bf16x8 qf = {};
    if (fg < 2) qf = *(const bf16x8*)(Q + base + (size_t)(q0 + fr) * 16 + fg * 8);

    float mrun[4], lrun[4];
    f32x4 acco = zero4;
    #pragma unroll
    for (int r = 0; r < 4; ++r) { mrun[r] = -1e30f; lrun[r] = 0.f; }

    for (int kc = 0; kc < 1024; kc += 32) {
      bf16x8 kf0 = {}, kf1 = {};
      if (fg < 2) {
        kf0 = *(const bf16x8*)(Ks + (kc + fr) * 24 + fg * 8);
        kf1 = *(const bf16x8*)(Ks + (kc + 16 + fr) * 24 + fg * 8);
      }
      f32x4 s0 = __builtin_amdgcn_mfma_f32_16x16x32_bf16(qf, kf0, zero4, 0, 0, 0);
      f32x4 s1 = __builtin_amdgcn_mfma_f32_16x16x32_bf16(qf, kf1, zero4, 0, 0, 0);

      #pragma unroll
      for (int r = 0; r < 4; ++r) {
        float a = s0[r] * SCALE_L2;
        float c = s1[r] * SCALE_L2;
        float mx = fmaxf(a, c);
        mx = fmaxf(mx, __shfl_xor(mx, 1));
        mx = fmaxf(mx, __shfl_xor(mx, 2));
        mx = fmaxf(mx, __shfl_xor(mx, 4));
        mx = fmaxf(mx, __shfl_xor(mx, 8));
        float mnew = fmaxf(mrun[r], mx);
        float alpha = exp2f(mrun[r] - mnew);
        float p0 = exp2f(a - mnew);
        float p1 = exp2f(c - mnew);
        float sum = p0 + p1;
        sum += __shfl_xor(sum, 1);
        sum += __shfl_xor(sum, 2);
        sum += __shfl_xor(sum, 4);
        sum += __shfl_xor(sum, 8);
        lrun[r] = lrun[r] * alpha + sum;
        mrun[r] = mnew;
        acco[r] *= alpha;
        Pw[(fg * 4 + r) * 40 + fr]      = f2bf(p0);
        Pw[(fg * 4 + r) * 40 + 16 + fr] = f2bf(p1);
      }
      // order: P stores -> (drain) -> P/V loads -> (fence) -> next iter stores.
      __asm__ volatile("s_waitcnt lgkmcnt(0)" ::: "memory");
      bf16x8 pf = *(const bf16x8*)(Pw + fr * 40 + fg * 8);
      bf16x8 vf = *(const bf16x8*)(Vt + fr * 1032 + kc + fg * 8);
      __asm__ volatile("" ::: "memory");   // keep next-iter stores below these loads
      acco = __builtin_amdgcn_mfma_f32_16x16x32_bf16(pf, vf, acco, 0, 0, 0);
    }

    #pragma unroll
    for (int r = 0; r < 4; ++r) {
      int row = q0 + fg * 4 + r;
      float v = acco[r] / lrun[r];
      outp[((size_t)(b * 1024 + row)) * 256 + h * 16 + fr] = f2bf(v);
    }
  }
}

// ---------------------------------------------------------------------------
// Instance-norm over axis n: partial sums (atomic) then apply. All fp32.
// ---------------------------------------------------------------------------
__global__ void stats_kernel(const float* __restrict__ y, float* __restrict__ ssum,
                             float* __restrict__ ssq)
{
  int bid = blockIdx.x;            // b*16 + chunk
  int b = bid >> 4, ch = bid & 15;
  int e = threadIdx.x;
  const float* p = y + ((size_t)b * 1024 + ch * 64) * 256 + e;
  float s = 0.f, q = 0.f;
  for (int r = 0; r < 64; ++r) { float v = p[(size_t)r * 256]; s += v; q += v * v; }
  atomicAdd(&ssum[b * 256 + e], s);
  atomicAdd(&ssq[b * 256 + e], q);
}

__global__ void apply_kernel(const float* __restrict__ y, const float* __restrict__ ssum,
                             const float* __restrict__ ssq, const float* __restrict__ gamma,
                             const float* __restrict__ beta, float* __restrict__ out)
{
  int idx = (blockIdx.x * 256 + threadIdx.x) * 4;
  int e = idx & 255;
  int b = idx >> 18;
  float4 v = *(const float4*)(y + idx);
  float vv[4] = {v.x, v.y, v.z, v.w};
  float ov[4];
  const float inv = 1.f / 1024.f;
  #pragma unroll
  for (int j = 0; j < 4; ++j) {
    int ej = e + j;
    float mean = ssum[b * 256 + ej] * inv;
    float var = ssq[b * 256 + ej] * inv - mean * mean;
    float rstd = rsqrtf(var + 1e-5f);
    ov[j] = (vv[j] - mean) * rstd * gamma[ej] + beta[ej];
  }
  *(float4*)(out + idx) = make_float4(ov[0], ov[1], ov[2], ov[3]);
}

// ---------------------------------------------------------------------------
extern "C" void kernel_launch(void* const* d_in, const int* in_sizes, int n_in,
                              void* d_out, int out_size, void* d_ws, size_t ws_size,
                              hipStream_t stream)
{
  const float* x      = (const float*)d_in[0];
  const float* Wq     = (const float*)d_in[1];
  const float* Wk     = (const float*)d_in[2];
  const float* Wv     = (const float*)d_in[3];
  const float* Wo     = (const float*)d_in[4];
  const float* bo     = (const float*)d_in[5];
  const float* gamma1 = (const float*)d_in[6];
  const float* beta1  = (const float*)d_in[7];
  const float* gamma2 = (const float*)d_in[8];
  const float* beta2  = (const float*)d_in[9];
  const float* W1     = (const float*)d_in[10];
  const float* b1     = (const float*)d_in[11];
  const float* W2     = (const float*)d_in[12];
  const float* b2     = (const float*)d_in[13];

  // Workspace layout (49.3 MB peak, lifetime-aliased):
  //   0         weights bf16 (QKVT 384K, WOT 128K, W1T 512K, W2T 256K)  [whole run]
  //   1310720   SS fp32 64K                                             [whole run]
  //   1376256   Qb 8M | Kb 8M | Vb 8M  bf16   (QKV gemm -> attn)
  //   26542080  ATTN 8M bf16                  (attn -> Wo gemm)
  //   1376256   Y 16M fp32   (aliases Qb+Kb; Wo gemm -> apply1, W2 gemm -> apply2)
  //   18153472  G 16M bf16   (aliases Vb+ATTN; GLU gemm -> W2 gemm)
  //   34930688  Hf 16M fp32  (apply1 -> GLU gemm A, W2 gemm res)   ends 51707904
  char* ws = (char*)d_ws;
  u16*   WQKVT = (u16*)(ws + 0);
  u16*   WOT   = (u16*)(ws + 393216);
  u16*   W1T   = (u16*)(ws + 524288);
  u16*   W2T   = (u16*)(ws + 1048576);
  float* SS    = (float*)(ws + 1310720);
  float* SSUM1 = SS;
  float* SSQ1  = SS + 4096;
  float* SSUM2 = SS + 8192;
  float* SSQ2  = SS + 12288;
  u16*   Qb    = (u16*)(ws + 1376256);
  u16*   ATTN  = (u16*)(ws + 26542080);
  float* Y     = (float*)(ws + 1376256);
  u16*   G     = (u16*)(ws + 18153472);
  float* Hf    = (float*)(ws + 34930688);

  hipMemsetAsync(SS, 0, 65536, stream);
  transpose_all<<<640, 256, 0, stream>>>(Wq, Wk, Wv, Wo, W1, W2, WQKVT, WOT, W1T, W2T);

  // QKV projection: (16384x256 fp32) @ (256x768 bf16) -> scatter bf16 [b][h][n][d]
  gemm_kernel<MODE_QKV, 1><<<dim3(128, 6), 256, 0, stream>>>(
      x, WQKVT, 16384, 768, 256, nullptr, nullptr, nullptr, Qb);

  attn_kernel<<<256, 512, 0, stream>>>(Qb, Qb + 4194304, Qb + 8388608, ATTN);

  // y1 = attn @ Wo + bo + x   (fp32 out, fp32 residual)
  gemm_kernel<MODE_Y_RES, 0><<<dim3(128, 2), 256, 0, stream>>>(
      ATTN, WOT, 16384, 256, 256, bo, x, Y, nullptr);

  stats_kernel<<<256, 256, 0, stream>>>(Y, SSUM1, SSQ1);
  apply_kernel<<<4096, 256, 0, stream>>>(Y, SSUM1, SSQ1, gamma1, beta1, Hf);

  // G = silu(gate) * x_part, fused into (h @ W1interleaved + b1) epilogue
  gemm_kernel<MODE_GLU, 1><<<dim3(128, 8), 256, 0, stream>>>(
      Hf, W1T, 16384, 1024, 256, b1, nullptr, nullptr, G);

  // y2 = G @ W2 + b2 + h   (fp32 out, fp32 residual)
  gemm_kernel<MODE_Y_RES, 0><<<dim3(128, 2), 256, 0, stream>>>(
      G, W2T, 16384, 256, 512, b2, Hf, Y, nullptr);

  stats_kernel<<<256, 256, 0, stream>>>(Y, SSUM2, SSQ2);
  apply_kernel<<<4096, 256, 0, stream>>>(Y, SSUM2, SSQ2, gamma2, beta2, (float*)d_out);
}

// Round 4
// 259.541 us; speedup vs baseline: 1.8201x; 1.8201x over previous
//
#include <hip/hip_runtime.h>
#include <stdint.h>

typedef unsigned short u16;
typedef __bf16 bf16x8 __attribute__((ext_vector_type(8)));
typedef float f32x4 __attribute__((ext_vector_type(4)));

__device__ __forceinline__ float bf2f(u16 v){ return __uint_as_float(((unsigned)v)<<16); }
__device__ __forceinline__ u16 f2bf(float f){
  unsigned u = __float_as_uint(f);
  unsigned r = (u + 0x7FFFu + ((u>>16)&1u)) >> 16;
  return (u16)r;
}
__device__ __forceinline__ float fexp2(float x){
#if __has_builtin(__builtin_amdgcn_exp2f)
  return __builtin_amdgcn_exp2f(x);
#else
  return exp2f(x);
#endif
}

// ---------------------------------------------------------------------------
// Fused transpose of all weights fp32 -> bf16 [n][k] (BT) layout.
// W1 column-interleaved for the fused SiLU-GLU epilogue.
// ---------------------------------------------------------------------------
__global__ void transpose_all(const float* __restrict__ Wq, const float* __restrict__ Wk,
                              const float* __restrict__ Wv, const float* __restrict__ Wo,
                              const float* __restrict__ W1, const float* __restrict__ W2,
                              u16* __restrict__ wqkvT, u16* __restrict__ woT,
                              u16* __restrict__ w1T, u16* __restrict__ w2T)
{
  __shared__ u16 tile[32][33];
  int bid = blockIdx.x;
  const float* in; u16* out; int K, N, t2; bool glu = false;
  if (bid < 64)       { in = Wq; out = wqkvT;           K = 256; N = 256;  t2 = bid; }
  else if (bid < 128) { in = Wk; out = wqkvT + 65536;   K = 256; N = 256;  t2 = bid - 64; }
  else if (bid < 192) { in = Wv; out = wqkvT + 131072;  K = 256; N = 256;  t2 = bid - 128; }
  else if (bid < 256) { in = Wo; out = woT;             K = 256; N = 256;  t2 = bid - 192; }
  else if (bid < 512) { in = W1; out = w1T;             K = 256; N = 1024; t2 = bid - 256; glu = true; }
  else                { in = W2; out = w2T;             K = 512; N = 256;  t2 = bid - 512; }
  int ntn = N >> 5;
  int k0 = (t2 / ntn) * 32, n0 = (t2 % ntn) * 32;
  int t = threadIdx.x;
  #pragma unroll
  for (int p = 0; p < 4; ++p) {
    int u = t + p * 256; int r = u >> 5, c = u & 31;
    tile[r][c] = f2bf(in[(size_t)(k0 + r) * N + n0 + c]);
  }
  __syncthreads();
  #pragma unroll
  for (int p = 0; p < 4; ++p) {
    int u = t + p * 256; int r = u >> 5, c = u & 31;
    int q = n0 + r;
    int row = glu ? (q < 512 ? 2 * q : 2 * (q - 512) + 1) : q;
    out[(size_t)row * K + k0 + c] = tile[c][r];
  }
}

// ---------------------------------------------------------------------------
// Generic 128x128-tile bf16 GEMM: C = A(MxK) * BT(NxK)^T, with epilogue modes.
// ---------------------------------------------------------------------------
enum { MODE_QKV = 0, MODE_Y_RES = 1, MODE_GLU = 2 };

template<int MODE, int AF32, int RESF32>
__launch_bounds__(256, 2)
__global__ void gemm_kernel(const void* __restrict__ Ap, const u16* __restrict__ BT,
                            int M, int N, int K,
                            const float* __restrict__ bias, const void* __restrict__ resp,
                            u16* __restrict__ outB)
{
  const float* Af = (const float*)Ap;
  const u16*   Ab = (const u16*)Ap;
  __shared__ u16 As[128 * 40];
  __shared__ u16 Bs[128 * 40];
  const int t = threadIdx.x;
  const int m0 = blockIdx.x * 128;
  const int n0 = blockIdx.y * 128;
  const int lane = t & 63;
  const int w = t >> 6;
  const int wm = (w >> 1) * 64;
  const int wn = (w & 1) * 64;
  const int fr = lane & 15;
  const int fg = lane >> 4;

  f32x4 acc[4][4];
  #pragma unroll
  for (int i = 0; i < 4; ++i)
    #pragma unroll
    for (int j = 0; j < 4; ++j)
      acc[i][j] = (f32x4){0.f, 0.f, 0.f, 0.f};

  for (int k0 = 0; k0 < K; k0 += 32) {
    __syncthreads();
    #pragma unroll
    for (int p = 0; p < 2; ++p) {
      int u = t + p * 256;
      int row = u >> 2, cb = u & 3;
      if (AF32) {
        const float* pa = Af + (size_t)(m0 + row) * K + k0 + cb * 8;
        float4 a0 = *(const float4*)pa;
        float4 a1 = *(const float4*)(pa + 4);
        union { u16 u[8]; uint4 v; } pk;
        pk.u[0] = f2bf(a0.x); pk.u[1] = f2bf(a0.y); pk.u[2] = f2bf(a0.z); pk.u[3] = f2bf(a0.w);
        pk.u[4] = f2bf(a1.x); pk.u[5] = f2bf(a1.y); pk.u[6] = f2bf(a1.z); pk.u[7] = f2bf(a1.w);
        *(uint4*)(As + row * 40 + cb * 8) = pk.v;
      } else {
        float4 va = *(const float4*)(Ab + (size_t)(m0 + row) * K + k0 + cb * 8);
        *(float4*)(As + row * 40 + cb * 8) = va;
      }
      float4 vb = *(const float4*)(BT + (size_t)(n0 + row) * K + k0 + cb * 8);
      *(float4*)(Bs + row * 40 + cb * 8) = vb;
    }
    __syncthreads();
    bf16x8 af[4], bfr[4];
    #pragma unroll
    for (int i = 0; i < 4; ++i) af[i]  = *(const bf16x8*)(As + (wm + i * 16 + fr) * 40 + fg * 8);
    #pragma unroll
    for (int j = 0; j < 4; ++j) bfr[j] = *(const bf16x8*)(Bs + (wn + j * 16 + fr) * 40 + fg * 8);
    #pragma unroll
    for (int i = 0; i < 4; ++i)
      #pragma unroll
      for (int j = 0; j < 4; ++j)
        acc[i][j] = __builtin_amdgcn_mfma_f32_16x16x32_bf16(af[i], bfr[j], acc[i][j], 0, 0, 0);
  }

  #pragma unroll
  for (int j = 0; j < 4; ++j) {
    int col = n0 + wn + j * 16 + fr;
    float bv = 0.f;
    if (MODE == MODE_Y_RES) bv = bias[col];
    if (MODE == MODE_GLU)   bv = bias[(col >> 1) + ((col & 1) << 9)];
    #pragma unroll
    for (int i = 0; i < 4; ++i) {
      #pragma unroll
      for (int r = 0; r < 4; ++r) {
        int row = m0 + wm + i * 16 + fg * 4 + r;
        float v = acc[i][j][r] + bv;
        if (MODE == MODE_QKV) {
          int which = col >> 8, h = (col >> 4) & 15, d = col & 15;
          int b = row >> 10, ns = row & 1023;
          outB[(size_t)which * 4194304 + (((size_t)(b * 16 + h) * 1024 + ns) * 16 + d)] = f2bf(v);
        } else if (MODE == MODE_Y_RES) {
          size_t idx = (size_t)row * N + col;
          float rv = RESF32 ? ((const float*)resp)[idx] : bf2f(((const u16*)resp)[idx]);
          outB[idx] = f2bf(v + rv);
        } else { // MODE_GLU
          float partner = __shfl_xor(v, 1);
          if ((fr & 1) == 0) {
            float g = partner / (1.f + __expf(-partner));  // silu(gate)
            outB[(size_t)row * 512 + (col >> 1)] = f2bf(g * v);
          }
        }
      }
    }
  }
}

// ---------------------------------------------------------------------------
// Attention, 2-way K-split, NO online max (scores provably tiny: |s|<~2.5).
// Block = (bh, split): 512 keys in LDS. Per-lane partial l; one reduce/tile.
// Keys interleaved (2*fr, 2*fr+1) so each lane's two P values pack into one
// ds_write_b32 via v_perm (truncate-to-bf16; bias cancels in normalization).
// Outputs unnormalized partial O (bf16) + partial l (fp32); combined later.
// ---------------------------------------------------------------------------
#define SCALE_L2 0.360673760222241f   /* (1/sqrt(16)) * log2(e) */

__launch_bounds__(512, 4)
__global__ void attn_kernel(const u16* __restrict__ Q, const u16* __restrict__ Kg,
                            const u16* __restrict__ Vg, u16* __restrict__ Op,
                            float* __restrict__ L)
{
  __shared__ u16 Ks[512 * 24];     // [key][d] padded 16->24
  __shared__ u16 Vt[16 * 520];     // [d][pos] padded 512->520 (pos = interleaved key)
  __shared__ u16 Pb[8 * 16 * 40];  // per-wave P buffer [16 rows][32 pos + pad]
  const int t = threadIdx.x;
  const int bh = blockIdx.x >> 1;
  const int s  = blockIdx.x & 1;
  const int b = bh >> 4, h = bh & 15;
  const size_t base = (size_t)bh * (1024 * 16);
  const size_t kbase = base + (size_t)(s * 512) * 16;

  #pragma unroll
  for (int u = t; u < 1024; u += 512) {
    int row = u >> 1, half = u & 1;
    float4 v = *(const float4*)(Kg + kbase + row * 16 + half * 8);
    *(float4*)(Ks + row * 24 + half * 8) = v;
  }
  #pragma unroll
  for (int u = t; u < 1024; u += 512) {
    int row = u >> 1, half = u & 1;
    const u16* src = Vg + kbase + row * 16 + half * 8;
    int pos = (row & ~31) + 2 * (row & 15) + ((row >> 4) & 1);
    #pragma unroll
    for (int j = 0; j < 8; ++j) Vt[(half * 8 + j) * 520 + pos] = src[j];
  }
  __syncthreads();

  const int w = t >> 6, lane = t & 63;
  const int fr = lane & 15, fg = lane >> 4;
  u16* Pw = Pb + w * (16 * 40);
  const f32x4 zero4 = (f32x4){0.f, 0.f, 0.f, 0.f};

  for (int qt = w; qt < 64; qt += 8) {
    const int q0 = qt * 16;
    bf16x8 qf = {};
    if (fg < 2) qf = *(const bf16x8*)(Q + base + (size_t)(q0 + fr) * 16 + fg * 8);

    float lsum[4] = {0.f, 0.f, 0.f, 0.f};
    f32x4 acco = zero4;

    #pragma unroll 2
    for (int kc = 0; kc < 512; kc += 32) {
      bf16x8 kf0 = {}, kf1 = {};
      if (fg < 2) {
        kf0 = *(const bf16x8*)(Ks + (kc + fr) * 24 + fg * 8);
        kf1 = *(const bf16x8*)(Ks + (kc + 16 + fr) * 24 + fg * 8);
      }
      f32x4 s0 = __builtin_amdgcn_mfma_f32_16x16x32_bf16(qf, kf0, zero4, 0, 0, 0);
      f32x4 s1 = __builtin_amdgcn_mfma_f32_16x16x32_bf16(qf, kf1, zero4, 0, 0, 0);

      #pragma unroll
      for (int r = 0; r < 4; ++r) {
        float p0 = fexp2(s0[r] * SCALE_L2);   // key kc+fr     -> pos kc+2*fr
        float p1 = fexp2(s1[r] * SCALE_L2);   // key kc+16+fr  -> pos kc+2*fr+1
        lsum[r] += p0 + p1;
        unsigned packed = __builtin_amdgcn_perm(__float_as_uint(p1), __float_as_uint(p0),
                                                0x07060302u);
        *(unsigned*)(Pw + (fg * 4 + r) * 40 + 2 * fr) = packed;
      }
      __asm__ volatile("s_waitcnt lgkmcnt(0)" ::: "memory");
      bf16x8 pf = *(const bf16x8*)(Pw + fr * 40 + fg * 8);
      bf16x8 vf = *(const bf16x8*)(Vt + fr * 520 + kc + fg * 8);
      __asm__ volatile("" ::: "memory");   // keep next-iter stores below these loads
      acco = __builtin_amdgcn_mfma_f32_16x16x32_bf16(pf, vf, acco, 0, 0, 0);
    }

    #pragma unroll
    for (int r = 0; r < 4; ++r) {
      float l = lsum[r];
      l += __shfl_xor(l, 1); l += __shfl_xor(l, 2);
      l += __shfl_xor(l, 4); l += __shfl_xor(l, 8);
      int row = q0 + fg * 4 + r;
      Op[(size_t)s * 4194304 + ((size_t)(b * 1024 + row) * 256 + h * 16 + fr)] = f2bf(acco[r]);
      if (fr == 0) L[s * 262144 + (b * 1024 + row) * 16 + h] = l;
    }
  }
}

// ---------------------------------------------------------------------------
// Combine the two K-split partials: attn = (O0 + O1) / (l0 + l1), bf16 out.
// ---------------------------------------------------------------------------
__global__ void combine_kernel(const u16* __restrict__ Op, const float* __restrict__ L,
                               u16* __restrict__ attn)
{
  int gtid = blockIdx.x * 256 + threadIdx.x;        // [b][q][h][dq]
  int h = (gtid >> 2) & 15, q = (gtid >> 6) & 1023, b = gtid >> 16;
  uint2 o0 = *(const uint2*)(Op + (size_t)gtid * 4);
  uint2 o1 = *(const uint2*)(Op + 4194304 + (size_t)gtid * 4);
  int li = (b * 1024 + q) * 16 + h;
  float inv = 1.f / (L[li] + L[262144 + li]);
  union { u16 u[4]; uint2 v; } a, c, o;
  a.v = o0; c.v = o1;
  #pragma unroll
  for (int j = 0; j < 4; ++j)
    o.u[j] = f2bf((bf2f(a.u[j]) + bf2f(c.u[j])) * inv);
  *(uint2*)(attn + (size_t)gtid * 4) = o.v;
}

// ---------------------------------------------------------------------------
// Instance-norm over axis n: partial sums (atomic) then apply. Y stored bf16.
// ---------------------------------------------------------------------------
__global__ void stats_kernel(const u16* __restrict__ y, float* __restrict__ ssum,
                             float* __restrict__ ssq)
{
  int bid = blockIdx.x;            // b*16 + chunk
  int b = bid >> 4, ch = bid & 15;
  int e = threadIdx.x;
  const u16* p = y + ((size_t)b * 1024 + ch * 64) * 256 + e;
  float s = 0.f, q = 0.f;
  for (int r = 0; r < 64; ++r) { float v = bf2f(p[(size_t)r * 256]); s += v; q += v * v; }
  atomicAdd(&ssum[b * 256 + e], s);
  atomicAdd(&ssq[b * 256 + e], q);
}

template<int OUTBF16>
__global__ void apply_kernel(const u16* __restrict__ y, const float* __restrict__ ssum,
                             const float* __restrict__ ssq, const float* __restrict__ gamma,
                             const float* __restrict__ beta, void* __restrict__ outp)
{
  int idx = (blockIdx.x * 256 + threadIdx.x) * 4;
  int e = idx & 255;
  int b = idx >> 18;
  union { u16 u[4]; uint2 v; } in;
  in.v = *(const uint2*)(y + idx);
  float ov[4];
  const float inv = 1.f / 1024.f;
  #pragma unroll
  for (int j = 0; j < 4; ++j) {
    int ej = e + j;
    float mean = ssum[b * 256 + ej] * inv;
    float var = ssq[b * 256 + ej] * inv - mean * mean;
    float rstd = rsqrtf(var + 1e-5f);
    ov[j] = (bf2f(in.u[j]) - mean) * rstd * gamma[ej] + beta[ej];
  }
  if (OUTBF16) {
    union { u16 u[4]; uint2 v; } pk;
    #pragma unroll
    for (int j = 0; j < 4; ++j) pk.u[j] = f2bf(ov[j]);
    *(uint2*)((u16*)outp + idx) = pk.v;
  } else {
    *(float4*)((float*)outp + idx) = make_float4(ov[0], ov[1], ov[2], ov[3]);
  }
}

// ---------------------------------------------------------------------------
extern "C" void kernel_launch(void* const* d_in, const int* in_sizes, int n_in,
                              void* d_out, int out_size, void* d_ws, size_t ws_size,
                              hipStream_t stream)
{
  const float* x      = (const float*)d_in[0];
  const float* Wq     = (const float*)d_in[1];
  const float* Wk     = (const float*)d_in[2];
  const float* Wv     = (const float*)d_in[3];
  const float* Wo     = (const float*)d_in[4];
  const float* bo     = (const float*)d_in[5];
  const float* gamma1 = (const float*)d_in[6];
  const float* beta1  = (const float*)d_in[7];
  const float* gamma2 = (const float*)d_in[8];
  const float* beta2  = (const float*)d_in[9];
  const float* W1     = (const float*)d_in[10];
  const float* b1     = (const float*)d_in[11];
  const float* W2     = (const float*)d_in[12];
  const float* b2     = (const float*)d_in[13];

  // Workspace (43.3 MB peak, lifetime-aliased):
  //  0         WT 1.25MB + SS 64K                       [permanent]
  //  1376256   QKV bf16 24MB      [qkv gemm -> attn]
  //  26542080  Op bf16 16MB       [attn -> combine]
  //  43319296  L fp32 2MB         [attn -> combine]     peak end 45416448
  //  1376256   ATTN bf16 8MB      [combine -> Wo gemm]   (alias QKV)
  //  9764864   Y1 bf16 8MB        [Wo gemm -> apply1]    (alias QKV)
  //  18153472  Hf bf16 8MB        [apply1 -> W2 gemm]    (alias QKV)
  //  26542080  G bf16 16MB        [GLU gemm -> W2 gemm]  (alias Op)
  //  1376256   Y2 bf16 8MB        [W2 gemm -> apply2]    (alias ATTN)
  char* ws = (char*)d_ws;
  u16*   WQKVT = (u16*)(ws + 0);
  u16*   WOT   = (u16*)(ws + 393216);
  u16*   W1T   = (u16*)(ws + 524288);
  u16*   W2T   = (u16*)(ws + 1048576);
  float* SS    = (float*)(ws + 1310720);
  float* SSUM1 = SS;
  float* SSQ1  = SS + 4096;
  float* SSUM2 = SS + 8192;
  float* SSQ2  = SS + 12288;
  u16*   Qb    = (u16*)(ws + 1376256);
  u16*   Op    = (u16*)(ws + 26542080);
  float* L     = (float*)(ws + 43319296);
  u16*   ATTN  = (u16*)(ws + 1376256);
  u16*   Y1    = (u16*)(ws + 9764864);
  u16*   Hf    = (u16*)(ws + 18153472);
  u16*   G     = (u16*)(ws + 26542080);
  u16*   Y2    = (u16*)(ws + 1376256);

  hipMemsetAsync(SS, 0, 65536, stream);
  transpose_all<<<640, 256, 0, stream>>>(Wq, Wk, Wv, Wo, W1, W2, WQKVT, WOT, W1T, W2T);

  // QKV projection: (16384x256 fp32) @ (256x768 bf16) -> scatter bf16 [b][h][n][d]
  gemm_kernel<MODE_QKV, 1, 0><<<dim3(128, 6), 256, 0, stream>>>(
      x, WQKVT, 16384, 768, 256, nullptr, nullptr, Qb);

  attn_kernel<<<512, 512, 0, stream>>>(Qb, Qb + 4194304, Qb + 8388608, Op, L);
  combine_kernel<<<4096, 256, 0, stream>>>(Op, L, ATTN);

  // y1 = attn @ Wo + bo + x   (res fp32, out bf16)
  gemm_kernel<MODE_Y_RES, 0, 1><<<dim3(128, 2), 256, 0, stream>>>(
      ATTN, WOT, 16384, 256, 256, bo, x, Y1);

  stats_kernel<<<256, 256, 0, stream>>>(Y1, SSUM1, SSQ1);
  apply_kernel<1><<<4096, 256, 0, stream>>>(Y1, SSUM1, SSQ1, gamma1, beta1, Hf);

  // G = silu(gate) * x_part, fused into (h @ W1interleaved + b1) epilogue
  gemm_kernel<MODE_GLU, 0, 0><<<dim3(128, 8), 256, 0, stream>>>(
      Hf, W1T, 16384, 1024, 256, b1, nullptr, G);

  // y2 = G @ W2 + b2 + h   (res bf16, out bf16)
  gemm_kernel<MODE_Y_RES, 0, 0><<<dim3(128, 2), 256, 0, stream>>>(
      G, W2T, 16384, 256, 512, b2, Hf, Y2);

  stats_kernel<<<256, 256, 0, stream>>>(Y2, SSUM2, SSQ2);
  apply_kernel<0><<<4096, 256, 0, stream>>>(Y2, SSUM2, SSQ2, gamma2, beta2, (float*)d_out);
}

// Round 5
// 245.157 us; speedup vs baseline: 1.9269x; 1.0587x over previous
//
#include <hip/hip_runtime.h>
#include <stdint.h>

typedef unsigned short u16;
typedef __bf16 bf16x8 __attribute__((ext_vector_type(8)));
typedef float f32x4 __attribute__((ext_vector_type(4)));

__device__ __forceinline__ float bf2f(u16 v){ return __uint_as_float(((unsigned)v)<<16); }
__device__ __forceinline__ u16 f2bf(float f){
  unsigned u = __float_as_uint(f);
  unsigned r = (u + 0x7FFFu + ((u>>16)&1u)) >> 16;
  return (u16)r;
}
__device__ __forceinline__ float fexp2(float x){
#if __has_builtin(__builtin_amdgcn_exp2f)
  return __builtin_amdgcn_exp2f(x);
#else
  return exp2f(x);
#endif
}

// ---------------------------------------------------------------------------
// Fused transpose of all weights fp32 -> bf16 [n][k] (BT) layout.
// W1 column-interleaved for the fused SiLU-GLU epilogue.
// ---------------------------------------------------------------------------
__global__ void transpose_all(const float* __restrict__ Wq, const float* __restrict__ Wk,
                              const float* __restrict__ Wv, const float* __restrict__ Wo,
                              const float* __restrict__ W1, const float* __restrict__ W2,
                              u16* __restrict__ wqkvT, u16* __restrict__ woT,
                              u16* __restrict__ w1T, u16* __restrict__ w2T)
{
  __shared__ u16 tile[32][33];
  int bid = blockIdx.x;
  const float* in; u16* out; int K, N, t2; bool glu = false;
  if (bid < 64)       { in = Wq; out = wqkvT;           K = 256; N = 256;  t2 = bid; }
  else if (bid < 128) { in = Wk; out = wqkvT + 65536;   K = 256; N = 256;  t2 = bid - 64; }
  else if (bid < 192) { in = Wv; out = wqkvT + 131072;  K = 256; N = 256;  t2 = bid - 128; }
  else if (bid < 256) { in = Wo; out = woT;             K = 256; N = 256;  t2 = bid - 192; }
  else if (bid < 512) { in = W1; out = w1T;             K = 256; N = 1024; t2 = bid - 256; glu = true; }
  else                { in = W2; out = w2T;             K = 512; N = 256;  t2 = bid - 512; }
  int ntn = N >> 5;
  int k0 = (t2 / ntn) * 32, n0 = (t2 % ntn) * 32;
  int t = threadIdx.x;
  #pragma unroll
  for (int p = 0; p < 4; ++p) {
    int u = t + p * 256; int r = u >> 5, c = u & 31;
    tile[r][c] = f2bf(in[(size_t)(k0 + r) * N + n0 + c]);
  }
  __syncthreads();
  #pragma unroll
  for (int p = 0; p < 4; ++p) {
    int u = t + p * 256; int r = u >> 5, c = u & 31;
    int q = n0 + r;
    int row = glu ? (q < 512 ? 2 * q : 2 * (q - 512) + 1) : q;
    out[(size_t)row * K + k0 + c] = tile[c][r];
  }
}

// ---------------------------------------------------------------------------
// x fp32 -> bf16 (done once; QKV GEMM then stages pure bf16)
// ---------------------------------------------------------------------------
__global__ void xconv(const float* __restrict__ x, u16* __restrict__ xb)
{
  int idx = (blockIdx.x * 256 + threadIdx.x) * 8;
  float4 a0 = *(const float4*)(x + idx);
  float4 a1 = *(const float4*)(x + idx + 4);
  union { u16 u[8]; uint4 v; } pk;
  pk.u[0] = f2bf(a0.x); pk.u[1] = f2bf(a0.y); pk.u[2] = f2bf(a0.z); pk.u[3] = f2bf(a0.w);
  pk.u[4] = f2bf(a1.x); pk.u[5] = f2bf(a1.y); pk.u[6] = f2bf(a1.z); pk.u[7] = f2bf(a1.w);
  *(uint4*)(xb + idx) = pk.v;
}

// ---------------------------------------------------------------------------
// Generic 128x128-tile bf16 GEMM: C = A(MxK) * BT(NxK)^T, with epilogue modes.
// STATS: fused instance-norm partial sums (per-column atomicAdd).
// ---------------------------------------------------------------------------
enum { MODE_QKV = 0, MODE_Y_RES = 1, MODE_GLU = 2 };

template<int MODE, int RESF32, int STATS>
__launch_bounds__(256, 2)
__global__ void gemm_kernel(const u16* __restrict__ A, const u16* __restrict__ BT,
                            int M, int N, int K,
                            const float* __restrict__ bias, const void* __restrict__ resp,
                            u16* __restrict__ outB,
                            float* __restrict__ ssum, float* __restrict__ ssq)
{
  __shared__ u16 As[128 * 40];
  __shared__ u16 Bs[128 * 40];
  const int t = threadIdx.x;
  const int m0 = blockIdx.x * 128;
  const int n0 = blockIdx.y * 128;
  const int lane = t & 63;
  const int w = t >> 6;
  const int wm = (w >> 1) * 64;
  const int wn = (w & 1) * 64;
  const int fr = lane & 15;
  const int fg = lane >> 4;

  f32x4 acc[4][4];
  #pragma unroll
  for (int i = 0; i < 4; ++i)
    #pragma unroll
    for (int j = 0; j < 4; ++j)
      acc[i][j] = (f32x4){0.f, 0.f, 0.f, 0.f};

  for (int k0 = 0; k0 < K; k0 += 32) {
    __syncthreads();
    #pragma unroll
    for (int p = 0; p < 2; ++p) {
      int u = t + p * 256;
      int row = u >> 2, cb = u & 3;
      float4 va = *(const float4*)(A + (size_t)(m0 + row) * K + k0 + cb * 8);
      *(float4*)(As + row * 40 + cb * 8) = va;
      float4 vb = *(const float4*)(BT + (size_t)(n0 + row) * K + k0 + cb * 8);
      *(float4*)(Bs + row * 40 + cb * 8) = vb;
    }
    __syncthreads();
    bf16x8 af[4], bfr[4];
    #pragma unroll
    for (int i = 0; i < 4; ++i) af[i]  = *(const bf16x8*)(As + (wm + i * 16 + fr) * 40 + fg * 8);
    #pragma unroll
    for (int j = 0; j < 4; ++j) bfr[j] = *(const bf16x8*)(Bs + (wn + j * 16 + fr) * 40 + fg * 8);
    #pragma unroll
    for (int i = 0; i < 4; ++i)
      #pragma unroll
      for (int j = 0; j < 4; ++j)
        acc[i][j] = __builtin_amdgcn_mfma_f32_16x16x32_bf16(af[i], bfr[j], acc[i][j], 0, 0, 0);
  }

  const int bIdx = m0 >> 10;   // batch of this m-tile (128 | 1024)
  #pragma unroll
  for (int j = 0; j < 4; ++j) {
    int col = n0 + wn + j * 16 + fr;
    float bv = 0.f;
    if (MODE == MODE_Y_RES) bv = bias[col];
    if (MODE == MODE_GLU)   bv = bias[(col >> 1) + ((col & 1) << 9)];
    float sj = 0.f, qj = 0.f;
    #pragma unroll
    for (int i = 0; i < 4; ++i) {
      #pragma unroll
      for (int r = 0; r < 4; ++r) {
        int row = m0 + wm + i * 16 + fg * 4 + r;
        float v = acc[i][j][r] + bv;
        if (MODE == MODE_QKV) {
          int which = col >> 8, h = (col >> 4) & 15, d = col & 15;
          int b = row >> 10, ns = row & 1023;
          outB[(size_t)which * 4194304 + (((size_t)(b * 16 + h) * 1024 + ns) * 16 + d)] = f2bf(v);
        } else if (MODE == MODE_Y_RES) {
          size_t idx = (size_t)row * N + col;
          float rv = RESF32 ? ((const float*)resp)[idx] : bf2f(((const u16*)resp)[idx]);
          float y = v + rv;
          outB[idx] = f2bf(y);
          if (STATS) { sj += y; qj += y * y; }
        } else { // MODE_GLU
          float partner = __shfl_xor(v, 1);
          if ((fr & 1) == 0) {
            float g = partner / (1.f + __expf(-partner));  // silu(gate)
            outB[(size_t)row * 512 + (col >> 1)] = f2bf(g * v);
          }
        }
      }
    }
    if (STATS) {
      sj += __shfl_xor(sj, 16); sj += __shfl_xor(sj, 32);
      qj += __shfl_xor(qj, 16); qj += __shfl_xor(qj, 32);
      if (fg == 0) {
        atomicAdd(&ssum[bIdx * 256 + col], sj);
        atomicAdd(&ssq[bIdx * 256 + col], qj);
      }
    }
  }
}

// ---------------------------------------------------------------------------
// Attention, K-streaming flash, no max-tracking (scores |s| < ~2.5).
// Block = (b, h, qgroup of 128 rows); each of 8 waves owns one 16-row Q-tile.
// 64-key K/V chunks staged in LDS per chunk (2 barriers/chunk); P round-trips
// per-wave LDS (C-layout -> A-layout); keys pair-interleaved so two bf16 P
// values pack into one ds_write_b32 via v_perm. SCALE folded into Q fragment.
// ---------------------------------------------------------------------------
#define SCALE_L2 0.360673760222241f   /* (1/sqrt(16)) * log2(e) */

__launch_bounds__(512, 4)
__global__ void attn_kernel(const u16* __restrict__ Q, const u16* __restrict__ Kg,
                            const u16* __restrict__ Vg, u16* __restrict__ attn)
{
  __shared__ u16 Ks[64 * 24];      // [key-in-chunk][d] padded 16->24
  __shared__ u16 Vt[16 * 72];      // [d][pos] pos=interleaved key-in-chunk, pad 64->72
  __shared__ u16 Pb[8 * 16 * 72];  // per-wave P [qrow][pos]
  const int t = threadIdx.x;
  const int bh = blockIdx.x >> 3;
  const int qg = blockIdx.x & 7;
  const int b = bh >> 4, h = bh & 15;
  const size_t base = (size_t)bh * 16384;
  const int w = t >> 6, lane = t & 63;
  const int fr = lane & 15, fg = lane >> 4;
  u16* Pw = Pb + w * (16 * 72);
  const int q0 = qg * 128 + w * 16;
  const f32x4 zero4 = (f32x4){0.f, 0.f, 0.f, 0.f};

  // Q fragment, pre-scaled by SCALE_L2 (so exp2 input is just the MFMA result)
  bf16x8 qf = {};
  if (fg < 2) {
    union { u16 u[8]; uint4 v; bf16x8 f; } qt;
    qt.v = *(const uint4*)(Q + base + (size_t)(q0 + fr) * 16 + fg * 8);
    #pragma unroll
    for (int j = 0; j < 8; ++j) qt.u[j] = f2bf(bf2f(qt.u[j]) * SCALE_L2);
    qf = qt.f;
  }

  f32x4 acco = zero4;
  float lsum[4] = {0.f, 0.f, 0.f, 0.f};

  for (int kc = 0; kc < 1024; kc += 64) {
    __syncthreads();   // previous chunk's reads done before overwrite
    if (t < 128) {           // waves 0-1: stage K chunk (raw copy)
      int row = t >> 1, half = t & 1;
      uint4 v = *(const uint4*)(Kg + base + (size_t)(kc + row) * 16 + half * 8);
      *(uint4*)(Ks + row * 24 + half * 8) = v;
    } else if (t < 256) {    // waves 2-3: stage V^T chunk (interleaved pos)
      int u = t - 128;
      int row = u >> 1, half = u & 1;
      const u16* src = Vg + base + (size_t)(kc + row) * 16 + half * 8;
      int idx = row & 31, sub = row >> 5;
      int pos = sub * 32 + (idx < 16 ? 2 * idx : 2 * (idx - 16) + 1);
      #pragma unroll
      for (int j = 0; j < 8; ++j) Vt[(half * 8 + j) * 72 + pos] = src[j];
    }
    __syncthreads();

    #pragma unroll
    for (int sub = 0; sub < 2; ++sub) {
      const int kb = sub * 32;
      bf16x8 kf0 = {}, kf1 = {};
      if (fg < 2) {
        kf0 = *(const bf16x8*)(Ks + (kb + fr) * 24 + fg * 8);
        kf1 = *(const bf16x8*)(Ks + (kb + 16 + fr) * 24 + fg * 8);
      }
      f32x4 s0 = __builtin_amdgcn_mfma_f32_16x16x32_bf16(qf, kf0, zero4, 0, 0, 0);
      f32x4 s1 = __builtin_amdgcn_mfma_f32_16x16x32_bf16(qf, kf1, zero4, 0, 0, 0);
      #pragma unroll
      for (int r = 0; r < 4; ++r) {
        float p0 = fexp2(s0[r]);   // key kb+fr     -> pos kb+2*fr
        float p1 = fexp2(s1[r]);   // key kb+16+fr  -> pos kb+2*fr+1
        lsum[r] += p0 + p1;
        *(unsigned*)(Pw + (fg * 4 + r) * 72 + kb + 2 * fr) =
            __builtin_amdgcn_perm(__float_as_uint(p1), __float_as_uint(p0), 0x07060302u);
      }
      __asm__ volatile("s_waitcnt lgkmcnt(0)" ::: "memory");
      bf16x8 pf = *(const bf16x8*)(Pw + fr * 72 + kb + fg * 8);
      bf16x8 vf = *(const bf16x8*)(Vt + fr * 72 + kb + fg * 8);
      __asm__ volatile("" ::: "memory");   // keep later stores below these loads
      acco = __builtin_amdgcn_mfma_f32_16x16x32_bf16(pf, vf, acco, 0, 0, 0);
    }
  }

  #pragma unroll
  for (int r = 0; r < 4; ++r) {
    float l = lsum[r];
    l += __shfl_xor(l, 1); l += __shfl_xor(l, 2);
    l += __shfl_xor(l, 4); l += __shfl_xor(l, 8);
    int row = q0 + fg * 4 + r;
    attn[((size_t)(b * 1024 + row)) * 256 + h * 16 + fr] = f2bf(acco[r] / l);
  }
}

// ---------------------------------------------------------------------------
// Instance-norm apply (stats produced by fused GEMM epilogues).
// ---------------------------------------------------------------------------
template<int OUTBF16>
__global__ void apply_kernel(const u16* __restrict__ y, const float* __restrict__ ssum,
                             const float* __restrict__ ssq, const float* __restrict__ gamma,
                             const float* __restrict__ beta, void* __restrict__ outp)
{
  int idx = (blockIdx.x * 256 + threadIdx.x) * 4;
  int e = idx & 255;
  int b = idx >> 18;
  union { u16 u[4]; uint2 v; } in;
  in.v = *(const uint2*)(y + idx);
  float ov[4];
  const float inv = 1.f / 1024.f;
  #pragma unroll
  for (int j = 0; j < 4; ++j) {
    int ej = e + j;
    float mean = ssum[b * 256 + ej] * inv;
    float var = ssq[b * 256 + ej] * inv - mean * mean;
    float rstd = rsqrtf(var + 1e-5f);
    ov[j] = (bf2f(in.u[j]) - mean) * rstd * gamma[ej] + beta[ej];
  }
  if (OUTBF16) {
    union { u16 u[4]; uint2 v; } pk;
    #pragma unroll
    for (int j = 0; j < 4; ++j) pk.u[j] = f2bf(ov[j]);
    *(uint2*)((u16*)outp + idx) = pk.v;
  } else {
    *(float4*)((float*)outp + idx) = make_float4(ov[0], ov[1], ov[2], ov[3]);
  }
}

// ---------------------------------------------------------------------------
extern "C" void kernel_launch(void* const* d_in, const int* in_sizes, int n_in,
                              void* d_out, int out_size, void* d_ws, size_t ws_size,
                              hipStream_t stream)
{
  const float* x      = (const float*)d_in[0];
  const float* Wq     = (const float*)d_in[1];
  const float* Wk     = (const float*)d_in[2];
  const float* Wv     = (const float*)d_in[3];
  const float* Wo     = (const float*)d_in[4];
  const float* bo     = (const float*)d_in[5];
  const float* gamma1 = (const float*)d_in[6];
  const float* beta1  = (const float*)d_in[7];
  const float* gamma2 = (const float*)d_in[8];
  const float* beta2  = (const float*)d_in[9];
  const float* W1     = (const float*)d_in[10];
  const float* b1     = (const float*)d_in[11];
  const float* W2     = (const float*)d_in[12];
  const float* b2     = (const float*)d_in[13];

  // Workspace (49.3 MB peak, lifetime-aliased; matches r3's proven footprint):
  //  0         WT 1.25MB + SS 64K                               [permanent]
  //  1376256   xb bf16 8MB      [xconv -> QKV gemm]
  //  9764864   Qb bf16 24MB     [QKV gemm -> attn]
  //  1376256   ATTN bf16 8MB    [attn -> Wo gemm]      (alias xb, dead)
  //  9764864   Y1 bf16 8MB      [Wo gemm -> apply1]    (alias Qb, dead)
  //  26542080  Hf bf16 8MB      [apply1 -> GLU A, W2 res]  (alias Qb upper)
  //  34930688  G bf16 16MB      [GLU gemm -> W2 gemm]  ends 51707904
  //  1376256   Y2 bf16 8MB      [W2 gemm -> apply2]    (alias ATTN, dead)
  char* ws = (char*)d_ws;
  u16*   WQKVT = (u16*)(ws + 0);
  u16*   WOT   = (u16*)(ws + 393216);
  u16*   W1T   = (u16*)(ws + 524288);
  u16*   W2T   = (u16*)(ws + 1048576);
  float* SS    = (float*)(ws + 1310720);
  float* SSUM1 = SS;
  float* SSQ1  = SS + 4096;
  float* SSUM2 = SS + 8192;
  float* SSQ2  = SS + 12288;
  u16*   xb    = (u16*)(ws + 1376256);
  u16*   Qb    = (u16*)(ws + 9764864);
  u16*   ATTN  = (u16*)(ws + 1376256);
  u16*   Y1    = (u16*)(ws + 9764864);
  u16*   Hf    = (u16*)(ws + 26542080);
  u16*   G     = (u16*)(ws + 34930688);
  u16*   Y2    = (u16*)(ws + 1376256);

  hipMemsetAsync(SS, 0, 65536, stream);
  transpose_all<<<640, 256, 0, stream>>>(Wq, Wk, Wv, Wo, W1, W2, WQKVT, WOT, W1T, W2T);
  xconv<<<2048, 256, 0, stream>>>(x, xb);

  // QKV projection: (16384x256) @ (256x768) -> scatter bf16 [b][h][n][d]
  gemm_kernel<MODE_QKV, 0, 0><<<dim3(128, 6), 256, 0, stream>>>(
      xb, WQKVT, 16384, 768, 256, nullptr, nullptr, Qb, nullptr, nullptr);

  attn_kernel<<<2048, 512, 0, stream>>>(Qb, Qb + 4194304, Qb + 8388608, ATTN);

  // y1 = attn @ Wo + bo + x   (res fp32 from d_in, out bf16, fused stats)
  gemm_kernel<MODE_Y_RES, 1, 1><<<dim3(128, 2), 256, 0, stream>>>(
      ATTN, WOT, 16384, 256, 256, bo, x, Y1, SSUM1, SSQ1);

  apply_kernel<1><<<4096, 256, 0, stream>>>(Y1, SSUM1, SSQ1, gamma1, beta1, Hf);

  // G = silu(gate) * x_part, fused into (h @ W1interleaved + b1) epilogue
  gemm_kernel<MODE_GLU, 0, 0><<<dim3(128, 8), 256, 0, stream>>>(
      Hf, W1T, 16384, 1024, 256, b1, nullptr, G, nullptr, nullptr);

  // y2 = G @ W2 + b2 + h   (res bf16, out bf16, fused stats)
  gemm_kernel<MODE_Y_RES, 0, 1><<<dim3(128, 2), 256, 0, stream>>>(
      G, W2T, 16384, 256, 512, b2, Hf, Y2, SSUM2, SSQ2);

  apply_kernel<0><<<4096, 256, 0, stream>>>(Y2, SSUM2, SSQ2, gamma2, beta2, (float*)d_out);
}

// Round 6
// 237.660 us; speedup vs baseline: 1.9877x; 1.0315x over previous
//
#include <hip/hip_runtime.h>
#include <stdint.h>

typedef unsigned short u16;
typedef __bf16 bf16x8 __attribute__((ext_vector_type(8)));
typedef float f32x4 __attribute__((ext_vector_type(4)));

__device__ __forceinline__ float bf2f(u16 v){ return __uint_as_float(((unsigned)v)<<16); }
__device__ __forceinline__ u16 f2bf(float f){
  unsigned u = __float_as_uint(f);
  unsigned r = (u + 0x7FFFu + ((u>>16)&1u)) >> 16;
  return (u16)r;
}
__device__ __forceinline__ float fexp2(float x){
#if __has_builtin(__builtin_amdgcn_exp2f)
  return __builtin_amdgcn_exp2f(x);
#else
  return exp2f(x);
#endif
}

// ---------------------------------------------------------------------------
// Fused: weight transpose fp32->bf16 [n][k] (blocks 0-639) + x fp32->bf16
// conversion (blocks 640-2687). W1 column-interleaved for fused SiLU-GLU.
// ---------------------------------------------------------------------------
__global__ void prep_kernel(const float* __restrict__ x_, u16* __restrict__ xb,
                            const float* __restrict__ Wq, const float* __restrict__ Wk,
                            const float* __restrict__ Wv, const float* __restrict__ Wo,
                            const float* __restrict__ W1, const float* __restrict__ W2,
                            u16* __restrict__ wqkvT, u16* __restrict__ woT,
                            u16* __restrict__ w1T, u16* __restrict__ w2T)
{
  int bid = blockIdx.x;
  int t = threadIdx.x;
  if (bid >= 640) {   // xconv path
    int idx = ((bid - 640) * 256 + t) * 8;
    float4 a0 = *(const float4*)(x_ + idx);
    float4 a1 = *(const float4*)(x_ + idx + 4);
    union { u16 u[8]; uint4 v; } pk;
    pk.u[0] = f2bf(a0.x); pk.u[1] = f2bf(a0.y); pk.u[2] = f2bf(a0.z); pk.u[3] = f2bf(a0.w);
    pk.u[4] = f2bf(a1.x); pk.u[5] = f2bf(a1.y); pk.u[6] = f2bf(a1.z); pk.u[7] = f2bf(a1.w);
    *(uint4*)(xb + idx) = pk.v;
    return;
  }
  __shared__ u16 tile[32][33];
  const float* in; u16* out; int K, N, t2; bool glu = false;
  if (bid < 64)       { in = Wq; out = wqkvT;           K = 256; N = 256;  t2 = bid; }
  else if (bid < 128) { in = Wk; out = wqkvT + 65536;   K = 256; N = 256;  t2 = bid - 64; }
  else if (bid < 192) { in = Wv; out = wqkvT + 131072;  K = 256; N = 256;  t2 = bid - 128; }
  else if (bid < 256) { in = Wo; out = woT;             K = 256; N = 256;  t2 = bid - 192; }
  else if (bid < 512) { in = W1; out = w1T;             K = 256; N = 1024; t2 = bid - 256; glu = true; }
  else                { in = W2; out = w2T;             K = 512; N = 256;  t2 = bid - 512; }
  int ntn = N >> 5;
  int k0 = (t2 / ntn) * 32, n0 = (t2 % ntn) * 32;
  #pragma unroll
  for (int p = 0; p < 4; ++p) {
    int u = t + p * 256; int r = u >> 5, c = u & 31;
    tile[r][c] = f2bf(in[(size_t)(k0 + r) * N + n0 + c]);
  }
  __syncthreads();
  #pragma unroll
  for (int p = 0; p < 4; ++p) {
    int u = t + p * 256; int r = u >> 5, c = u & 31;
    int q = n0 + r;
    int row = glu ? (q < 512 ? 2 * q : 2 * (q - 512) + 1) : q;
    out[(size_t)row * K + k0 + c] = tile[c][r];
  }
}

// ---------------------------------------------------------------------------
// Generic 128x128-tile bf16 GEMM: C = A(MxK) * BT(NxK)^T, with epilogue modes.
// STATS: fused instance-norm partial sums (per-column atomicAdd).
// ---------------------------------------------------------------------------
enum { MODE_QKV = 0, MODE_Y_RES = 1, MODE_GLU = 2 };

template<int MODE, int RESF32, int STATS>
__launch_bounds__(256, 2)
__global__ void gemm_kernel(const u16* __restrict__ A, const u16* __restrict__ BT,
                            int M, int N, int K,
                            const float* __restrict__ bias, const void* __restrict__ resp,
                            u16* __restrict__ outB,
                            float* __restrict__ ssum, float* __restrict__ ssq)
{
  __shared__ u16 As[128 * 40];
  __shared__ u16 Bs[128 * 40];
  const int t = threadIdx.x;
  const int m0 = blockIdx.x * 128;
  const int n0 = blockIdx.y * 128;
  const int lane = t & 63;
  const int w = t >> 6;
  const int wm = (w >> 1) * 64;
  const int wn = (w & 1) * 64;
  const int fr = lane & 15;
  const int fg = lane >> 4;

  f32x4 acc[4][4];
  #pragma unroll
  for (int i = 0; i < 4; ++i)
    #pragma unroll
    for (int j = 0; j < 4; ++j)
      acc[i][j] = (f32x4){0.f, 0.f, 0.f, 0.f};

  for (int k0 = 0; k0 < K; k0 += 32) {
    __syncthreads();
    #pragma unroll
    for (int p = 0; p < 2; ++p) {
      int u = t + p * 256;
      int row = u >> 2, cb = u & 3;
      float4 va = *(const float4*)(A + (size_t)(m0 + row) * K + k0 + cb * 8);
      *(float4*)(As + row * 40 + cb * 8) = va;
      float4 vb = *(const float4*)(BT + (size_t)(n0 + row) * K + k0 + cb * 8);
      *(float4*)(Bs + row * 40 + cb * 8) = vb;
    }
    __syncthreads();
    bf16x8 af[4], bfr[4];
    #pragma unroll
    for (int i = 0; i < 4; ++i) af[i]  = *(const bf16x8*)(As + (wm + i * 16 + fr) * 40 + fg * 8);
    #pragma unroll
    for (int j = 0; j < 4; ++j) bfr[j] = *(const bf16x8*)(Bs + (wn + j * 16 + fr) * 40 + fg * 8);
    #pragma unroll
    for (int i = 0; i < 4; ++i)
      #pragma unroll
      for (int j = 0; j < 4; ++j)
        acc[i][j] = __builtin_amdgcn_mfma_f32_16x16x32_bf16(af[i], bfr[j], acc[i][j], 0, 0, 0);
  }

  const int bIdx = m0 >> 10;
  #pragma unroll
  for (int j = 0; j < 4; ++j) {
    int col = n0 + wn + j * 16 + fr;
    float bv = 0.f;
    if (MODE == MODE_Y_RES) bv = bias[col];
    if (MODE == MODE_GLU)   bv = bias[(col >> 1) + ((col & 1) << 9)];
    float sj = 0.f, qj = 0.f;
    #pragma unroll
    for (int i = 0; i < 4; ++i) {
      #pragma unroll
      for (int r = 0; r < 4; ++r) {
        int row = m0 + wm + i * 16 + fg * 4 + r;
        float v = acc[i][j][r] + bv;
        if (MODE == MODE_QKV) {
          int which = col >> 8, h = (col >> 4) & 15, d = col & 15;
          int b = row >> 10, ns = row & 1023;
          outB[(size_t)which * 4194304 + (((size_t)(b * 16 + h) * 1024 + ns) * 16 + d)] = f2bf(v);
        } else if (MODE == MODE_Y_RES) {
          size_t idx = (size_t)row * N + col;
          float rv = RESF32 ? ((const float*)resp)[idx] : bf2f(((const u16*)resp)[idx]);
          float y = v + rv;
          outB[idx] = f2bf(y);
          if (STATS) { sj += y; qj += y * y; }
        } else { // MODE_GLU
          float partner = __shfl_xor(v, 1);
          if ((fr & 1) == 0) {
            float g = partner / (1.f + __expf(-partner));  // silu(gate)
            outB[(size_t)row * 512 + (col >> 1)] = f2bf(g * v);
          }
        }
      }
    }
    if (STATS) {
      sj += __shfl_xor(sj, 16); sj += __shfl_xor(sj, 32);
      qj += __shfl_xor(qj, 16); qj += __shfl_xor(qj, 32);
      if (fg == 0) {
        atomicAdd(&ssum[bIdx * 256 + col], sj);
        atomicAdd(&ssq[bIdx * 256 + col], qj);
      }
    }
  }
}

// ---------------------------------------------------------------------------
// Attention v3: K-streaming flash, no max-tracking (|s| < ~2.5), 128-key
// chunks, double-buffered LDS with register prefetch (1 barrier/chunk).
// K rows staged at pair-permuted positions (even key i -> pos i/2, odd ->
// 16+i/2 within each 32-block) with vectorized writes, so P packs pairwise
// (v_perm + one ds_write_b32) while V^T keeps natural key order.
// Block = (qg, bh) with bh = bid&255 so all 8 q-groups of one (b,h) share
// an XCD (bid%8 heuristic) for K/V L2 reuse.
// ---------------------------------------------------------------------------
#define SCALE_L2 0.360673760222241f   /* (1/sqrt(16)) * log2(e) */

__launch_bounds__(512, 4)
__global__ void attn_kernel(const u16* __restrict__ Q, const u16* __restrict__ Kg,
                            const u16* __restrict__ Vg, u16* __restrict__ attn)
{
  __shared__ u16 Ks[2][128 * 24];   // [buf][pos][d] d padded 16->24
  __shared__ u16 Vt[2][16 * 136];   // [buf][d][key] key padded 128->136
  __shared__ u16 Pb[8][16 * 40];    // per-wave P [qrow][key-in-32 + pad]
  const int t = threadIdx.x;
  const int bh = blockIdx.x & 255;
  const int qg = blockIdx.x >> 8;
  const int b = bh >> 4, h = bh & 15;
  const size_t base = (size_t)bh * 16384;
  const int w = t >> 6, lane = t & 63;
  const int fr = lane & 15, fg = lane >> 4;
  u16* Pw = Pb[w];
  const int q0 = qg * 128 + w * 16;
  const f32x4 zero4 = (f32x4){0.f, 0.f, 0.f, 0.f};

  // staging roles: threads 0-255 stage K, 256-511 stage V (wave-uniform)
  const int su = (t & 255) >> 1;    // key-in-chunk 0..127
  const int sh = t & 1;             // which 8-d half
  const bool isK = t < 256;
  const int blk = su >> 5, ii = su & 31;
  const int kpos = blk * 32 + ((ii & 1) ? 16 + (ii >> 1) : (ii >> 1));

  // Q fragment, pre-scaled by SCALE_L2
  bf16x8 qf = {};
  if (fg < 2) {
    union { u16 u[8]; uint4 v; bf16x8 f; } qt;
    qt.v = *(const uint4*)(Q + base + (size_t)(q0 + fr) * 16 + fg * 8);
    #pragma unroll
    for (int j = 0; j < 8; ++j) qt.u[j] = f2bf(bf2f(qt.u[j]) * SCALE_L2);
    qf = qt.f;
  }

  // preload chunk 0
  {
    uint4 pre = isK ? *(const uint4*)(Kg + base + (size_t)su * 16 + sh * 8)
                    : *(const uint4*)(Vg + base + (size_t)su * 16 + sh * 8);
    if (isK) {
      *(uint4*)(&Ks[0][kpos * 24 + sh * 8]) = pre;
    } else {
      union { u16 u[8]; uint4 v; } pk; pk.v = pre;
      #pragma unroll
      for (int j = 0; j < 8; ++j) Vt[0][(sh * 8 + j) * 136 + su] = pk.u[j];
    }
  }
  __syncthreads();

  f32x4 acco = zero4;
  float lsum[4] = {0.f, 0.f, 0.f, 0.f};

  for (int c = 0; c < 8; ++c) {
    uint4 nxt;
    if (c < 7) {   // register prefetch of chunk c+1 (latency hidden by compute)
      const size_t off = base + (size_t)((c + 1) * 128 + su) * 16 + sh * 8;
      nxt = isK ? *(const uint4*)(Kg + off) : *(const uint4*)(Vg + off);
    }
    const u16* KsC = Ks[c & 1];
    const u16* VtC = Vt[c & 1];
    #pragma unroll
    for (int sub = 0; sub < 4; ++sub) {
      const int kb = sub * 32;
      bf16x8 kf0 = {}, kf1 = {};
      if (fg < 2) {
        kf0 = *(const bf16x8*)(KsC + (kb + fr) * 24 + fg * 8);
        kf1 = *(const bf16x8*)(KsC + (kb + 16 + fr) * 24 + fg * 8);
      }
      f32x4 s0 = __builtin_amdgcn_mfma_f32_16x16x32_bf16(qf, kf0, zero4, 0, 0, 0);
      f32x4 s1 = __builtin_amdgcn_mfma_f32_16x16x32_bf16(qf, kf1, zero4, 0, 0, 0);
      #pragma unroll
      for (int r = 0; r < 4; ++r) {
        float p0 = fexp2(s0[r]);   // pos kb+fr     = key kb+2*fr
        float p1 = fexp2(s1[r]);   // pos kb+16+fr  = key kb+2*fr+1
        lsum[r] += p0 + p1;
        *(unsigned*)(Pw + (fg * 4 + r) * 40 + 2 * fr) =
            __builtin_amdgcn_perm(__float_as_uint(p1), __float_as_uint(p0), 0x07060302u);
      }
      __asm__ volatile("s_waitcnt lgkmcnt(0)" ::: "memory");
      bf16x8 pf = *(const bf16x8*)(Pw + fr * 40 + fg * 8);
      bf16x8 vf = *(const bf16x8*)(VtC + fr * 136 + kb + fg * 8);
      __asm__ volatile("" ::: "memory");   // keep later P stores below these loads
      acco = __builtin_amdgcn_mfma_f32_16x16x32_bf16(pf, vf, acco, 0, 0, 0);
    }
    if (c < 7) {   // write prefetched chunk into the other buffer
      if (isK) {
        *(uint4*)(&Ks[(c + 1) & 1][kpos * 24 + sh * 8]) = nxt;
      } else {
        union { u16 u[8]; uint4 v; } pk; pk.v = nxt;
        #pragma unroll
        for (int j = 0; j < 8; ++j) Vt[(c + 1) & 1][(sh * 8 + j) * 136 + su] = pk.u[j];
      }
    }
    __syncthreads();
  }

  #pragma unroll
  for (int r = 0; r < 4; ++r) {
    float l = lsum[r];
    l += __shfl_xor(l, 1); l += __shfl_xor(l, 2);
    l += __shfl_xor(l, 4); l += __shfl_xor(l, 8);
    int row = q0 + fg * 4 + r;
    attn[((size_t)(b * 1024 + row)) * 256 + h * 16 + fr] = f2bf(acco[r] / l);
  }
}

// ---------------------------------------------------------------------------
// Instance-norm apply (stats produced by fused GEMM epilogues).
// ---------------------------------------------------------------------------
template<int OUTBF16>
__global__ void apply_kernel(const u16* __restrict__ y, const float* __restrict__ ssum,
                             const float* __restrict__ ssq, const float* __restrict__ gamma,
                             const float* __restrict__ beta, void* __restrict__ outp)
{
  int idx = (blockIdx.x * 256 + threadIdx.x) * 4;
  int e = idx & 255;
  int b = idx >> 18;
  union { u16 u[4]; uint2 v; } in;
  in.v = *(const uint2*)(y + idx);
  float ov[4];
  const float inv = 1.f / 1024.f;
  #pragma unroll
  for (int j = 0; j < 4; ++j) {
    int ej = e + j;
    float mean = ssum[b * 256 + ej] * inv;
    float var = ssq[b * 256 + ej] * inv - mean * mean;
    float rstd = rsqrtf(var + 1e-5f);
    ov[j] = (bf2f(in.u[j]) - mean) * rstd * gamma[ej] + beta[ej];
  }
  if (OUTBF16) {
    union { u16 u[4]; uint2 v; } pk;
    #pragma unroll
    for (int j = 0; j < 4; ++j) pk.u[j] = f2bf(ov[j]);
    *(uint2*)((u16*)outp + idx) = pk.v;
  } else {
    *(float4*)((float*)outp + idx) = make_float4(ov[0], ov[1], ov[2], ov[3]);
  }
}

// ---------------------------------------------------------------------------
extern "C" void kernel_launch(void* const* d_in, const int* in_sizes, int n_in,
                              void* d_out, int out_size, void* d_ws, size_t ws_size,
                              hipStream_t stream)
{
  const float* x      = (const float*)d_in[0];
  const float* Wq     = (const float*)d_in[1];
  const float* Wk     = (const float*)d_in[2];
  const float* Wv     = (const float*)d_in[3];
  const float* Wo     = (const float*)d_in[4];
  const float* bo     = (const float*)d_in[5];
  const float* gamma1 = (const float*)d_in[6];
  const float* beta1  = (const float*)d_in[7];
  const float* gamma2 = (const float*)d_in[8];
  const float* beta2  = (const float*)d_in[9];
  const float* W1     = (const float*)d_in[10];
  const float* b1     = (const float*)d_in[11];
  const float* W2     = (const float*)d_in[12];
  const float* b2     = (const float*)d_in[13];

  // Workspace (49.3 MB peak, lifetime-aliased; proven footprint):
  //  0         WT 1.25MB + SS 64K                               [permanent]
  //  1376256   xb bf16 8MB      [prep -> QKV gemm]
  //  9764864   Qb bf16 24MB     [QKV gemm -> attn]
  //  1376256   ATTN bf16 8MB    [attn -> Wo gemm]      (alias xb, dead)
  //  9764864   Y1 bf16 8MB      [Wo gemm -> apply1]    (alias Qb, dead)
  //  26542080  Hf bf16 8MB      [apply1 -> GLU A, W2 res]  (alias Qb upper)
  //  34930688  G bf16 16MB      [GLU gemm -> W2 gemm]  ends 51707904
  //  1376256   Y2 bf16 8MB      [W2 gemm -> apply2]    (alias ATTN, dead)
  char* ws = (char*)d_ws;
  u16*   WQKVT = (u16*)(ws + 0);
  u16*   WOT   = (u16*)(ws + 393216);
  u16*   W1T   = (u16*)(ws + 524288);
  u16*   W2T   = (u16*)(ws + 1048576);
  float* SS    = (float*)(ws + 1310720);
  float* SSUM1 = SS;
  float* SSQ1  = SS + 4096;
  float* SSUM2 = SS + 8192;
  float* SSQ2  = SS + 12288;
  u16*   xb    = (u16*)(ws + 1376256);
  u16*   Qb    = (u16*)(ws + 9764864);
  u16*   ATTN  = (u16*)(ws + 1376256);
  u16*   Y1    = (u16*)(ws + 9764864);
  u16*   Hf    = (u16*)(ws + 26542080);
  u16*   G     = (u16*)(ws + 34930688);
  u16*   Y2    = (u16*)(ws + 1376256);

  hipMemsetAsync(SS, 0, 65536, stream);
  prep_kernel<<<2688, 256, 0, stream>>>(x, xb, Wq, Wk, Wv, Wo, W1, W2,
                                        WQKVT, WOT, W1T, W2T);

  // QKV projection: (16384x256) @ (256x768) -> scatter bf16 [b][h][n][d]
  gemm_kernel<MODE_QKV, 0, 0><<<dim3(128, 6), 256, 0, stream>>>(
      xb, WQKVT, 16384, 768, 256, nullptr, nullptr, Qb, nullptr, nullptr);

  attn_kernel<<<2048, 512, 0, stream>>>(Qb, Qb + 4194304, Qb + 8388608, ATTN);

  // y1 = attn @ Wo + bo + x   (res fp32 from d_in, out bf16, fused stats)
  gemm_kernel<MODE_Y_RES, 1, 1><<<dim3(128, 2), 256, 0, stream>>>(
      ATTN, WOT, 16384, 256, 256, bo, x, Y1, SSUM1, SSQ1);

  apply_kernel<1><<<4096, 256, 0, stream>>>(Y1, SSUM1, SSQ1, gamma1, beta1, Hf);

  // G = silu(gate) * x_part, fused into (h @ W1interleaved + b1) epilogue
  gemm_kernel<MODE_GLU, 0, 0><<<dim3(128, 8), 256, 0, stream>>>(
      Hf, W1T, 16384, 1024, 256, b1, nullptr, G, nullptr, nullptr);

  // y2 = G @ W2 + b2 + h   (res bf16, out bf16, fused stats)
  gemm_kernel<MODE_Y_RES, 0, 1><<<dim3(128, 2), 256, 0, stream>>>(
      G, W2T, 16384, 256, 512, b2, Hf, Y2, SSUM2, SSQ2);

  apply_kernel<0><<<4096, 256, 0, stream>>>(Y2, SSUM2, SSQ2, gamma2, beta2, (float*)d_out);
}

// Round 7
// 225.914 us; speedup vs baseline: 2.0910x; 1.0520x over previous
//
#include <hip/hip_runtime.h>
#include <stdint.h>

typedef unsigned short u16;
typedef __bf16 bf16x8 __attribute__((ext_vector_type(8)));
typedef float f32x4 __attribute__((ext_vector_type(4)));

__device__ __forceinline__ float bf2f(u16 v){ return __uint_as_float(((unsigned)v)<<16); }
__device__ __forceinline__ u16 f2bf(float f){
  unsigned u = __float_as_uint(f);
  unsigned r = (u + 0x7FFFu + ((u>>16)&1u)) >> 16;
  return (u16)r;
}
__device__ __forceinline__ float fexp2(float x){
#if __has_builtin(__builtin_amdgcn_exp2f)
  return __builtin_amdgcn_exp2f(x);
#else
  return exp2f(x);
#endif
}

// ---------------------------------------------------------------------------
// Prep: weight transpose fp32->bf16 [n][k] (blocks 0-639, blocks 0-63 also
// zero the stats buffer) + x fp32->bf16 (blocks 640-2687).
// W1 column-interleaved for fused SiLU-GLU.
// ---------------------------------------------------------------------------
__global__ void prep_kernel(const float* __restrict__ x_, u16* __restrict__ xb,
                            const float* __restrict__ Wq, const float* __restrict__ Wk,
                            const float* __restrict__ Wv, const float* __restrict__ Wo,
                            const float* __restrict__ W1, const float* __restrict__ W2,
                            u16* __restrict__ wqkvT, u16* __restrict__ woT,
                            u16* __restrict__ w1T, u16* __restrict__ w2T,
                            float* __restrict__ SS)
{
  int bid = blockIdx.x;
  int t = threadIdx.x;
  if (bid >= 640) {   // xconv path
    int idx = ((bid - 640) * 256 + t) * 8;
    float4 a0 = *(const float4*)(x_ + idx);
    float4 a1 = *(const float4*)(x_ + idx + 4);
    union { u16 u[8]; uint4 v; } pk;
    pk.u[0] = f2bf(a0.x); pk.u[1] = f2bf(a0.y); pk.u[2] = f2bf(a0.z); pk.u[3] = f2bf(a0.w);
    pk.u[4] = f2bf(a1.x); pk.u[5] = f2bf(a1.y); pk.u[6] = f2bf(a1.z); pk.u[7] = f2bf(a1.w);
    *(uint4*)(xb + idx) = pk.v;
    return;
  }
  if (bid < 64) SS[bid * 256 + t] = 0.f;   // zero 16384-float stats region
  __shared__ u16 tile[32][33];
  const float* in; u16* out; int K, N, t2; bool glu = false;
  if (bid < 64)       { in = Wq; out = wqkvT;           K = 256; N = 256;  t2 = bid; }
  else if (bid < 128) { in = Wk; out = wqkvT + 65536;   K = 256; N = 256;  t2 = bid - 64; }
  else if (bid < 192) { in = Wv; out = wqkvT + 131072;  K = 256; N = 256;  t2 = bid - 128; }
  else if (bid < 256) { in = Wo; out = woT;             K = 256; N = 256;  t2 = bid - 192; }
  else if (bid < 512) { in = W1; out = w1T;             K = 256; N = 1024; t2 = bid - 256; glu = true; }
  else                { in = W2; out = w2T;             K = 512; N = 256;  t2 = bid - 512; }
  int ntn = N >> 5;
  int k0 = (t2 / ntn) * 32, n0 = (t2 % ntn) * 32;
  #pragma unroll
  for (int p = 0; p < 4; ++p) {
    int u = t + p * 256; int r = u >> 5, c = u & 31;
    tile[r][c] = f2bf(in[(size_t)(k0 + r) * N + n0 + c]);
  }
  __syncthreads();
  #pragma unroll
  for (int p = 0; p < 4; ++p) {
    int u = t + p * 256; int r = u >> 5, c = u & 31;
    int q = n0 + r;
    int row = glu ? (q < 512 ? 2 * q : 2 * (q - 512) + 1) : q;
    out[(size_t)row * K + k0 + c] = tile[c][r];
  }
}

// ---------------------------------------------------------------------------
// 128xTN-tile bf16 GEMM: C = A(MxK) * BT(NxK)^T.
// RESN: 0 none, 1 plain bf16 residual, 2 residual = instnorm(resp) w/ n-stats.
// STATS: fused instance-norm partial sums into ssum/ssq (atomics).
// NORMA: A is normalized during LDS staging using n-stats (per-block b const).
// ---------------------------------------------------------------------------
enum { MODE_QKV = 0, MODE_Y_RES = 1, MODE_GLU = 2 };

template<int MODE, int TN, int RESN, int STATS, int NORMA>
__launch_bounds__(256, 3)
__global__ void gemm_kernel(const u16* __restrict__ A, const u16* __restrict__ BT,
                            int M, int N, int K,
                            const float* __restrict__ bias, const u16* __restrict__ resp,
                            u16* __restrict__ outB,
                            float* __restrict__ ssum, float* __restrict__ ssq,
                            const float* __restrict__ nsum, const float* __restrict__ nsq,
                            const float* __restrict__ ngam, const float* __restrict__ nbet)
{
  constexpr int NJ = TN / 32;          // 4 for TN=128, 2 for TN=64
  __shared__ u16 As[128 * 40];
  __shared__ u16 Bs[TN * 40];
  __shared__ float scA[256], sfA[256];
  const int t = threadIdx.x;
  const int m0 = blockIdx.x * 128;
  const int n0 = blockIdx.y * TN;
  const int lane = t & 63;
  const int w = t >> 6;
  const int wm = (w >> 1) * 64;
  const int wn = (w & 1) * (NJ * 16);
  const int fr = lane & 15;
  const int fg = lane >> 4;
  const int bIdx = m0 >> 10;
  const float inv1024 = 1.f / 1024.f;

  if (NORMA) {
    int e = t;
    float mean = nsum[bIdx * 256 + e] * inv1024;
    float var = nsq[bIdx * 256 + e] * inv1024 - mean * mean;
    float rstd = rsqrtf(var + 1e-5f);
    float sc = rstd * ngam[e];
    scA[e] = sc;
    sfA[e] = nbet[e] - mean * sc;
  }

  f32x4 acc[4][NJ];
  #pragma unroll
  for (int i = 0; i < 4; ++i)
    #pragma unroll
    for (int j = 0; j < NJ; ++j)
      acc[i][j] = (f32x4){0.f, 0.f, 0.f, 0.f};

  constexpr int TOT = (128 + TN) * 4;   // 8-elem staging units
  for (int k0 = 0; k0 < K; k0 += 32) {
    __syncthreads();
    #pragma unroll
    for (int u = 0; u < TOT / 256; ++u) {
      int uu = t + u * 256;
      if (uu < 512) {
        int row = uu >> 2, cb = uu & 3;
        if (NORMA) {
          union { u16 u[8]; uint4 v; } in, o;
          in.v = *(const uint4*)(A + (size_t)(m0 + row) * K + k0 + cb * 8);
          const float* scp = scA + k0 + cb * 8;
          const float* sfp = sfA + k0 + cb * 8;
          float4 s0 = *(const float4*)scp, s1 = *(const float4*)(scp + 4);
          float4 f0 = *(const float4*)sfp, f1 = *(const float4*)(sfp + 4);
          o.u[0] = f2bf(bf2f(in.u[0]) * s0.x + f0.x);
          o.u[1] = f2bf(bf2f(in.u[1]) * s0.y + f0.y);
          o.u[2] = f2bf(bf2f(in.u[2]) * s0.z + f0.z);
          o.u[3] = f2bf(bf2f(in.u[3]) * s0.w + f0.w);
          o.u[4] = f2bf(bf2f(in.u[4]) * s1.x + f1.x);
          o.u[5] = f2bf(bf2f(in.u[5]) * s1.y + f1.y);
          o.u[6] = f2bf(bf2f(in.u[6]) * s1.z + f1.z);
          o.u[7] = f2bf(bf2f(in.u[7]) * s1.w + f1.w);
          *(uint4*)(As + row * 40 + cb * 8) = o.v;
        } else {
          float4 va = *(const float4*)(A + (size_t)(m0 + row) * K + k0 + cb * 8);
          *(float4*)(As + row * 40 + cb * 8) = va;
        }
      } else {
        int v2 = uu - 512;
        int row = v2 >> 2, cb = v2 & 3;
        float4 vb = *(const float4*)(BT + (size_t)(n0 + row) * K + k0 + cb * 8);
        *(float4*)(Bs + row * 40 + cb * 8) = vb;
      }
    }
    __syncthreads();
    bf16x8 af[4], bfr[NJ];
    #pragma unroll
    for (int i = 0; i < 4; ++i) af[i]  = *(const bf16x8*)(As + (wm + i * 16 + fr) * 40 + fg * 8);
    #pragma unroll
    for (int j = 0; j < NJ; ++j) bfr[j] = *(const bf16x8*)(Bs + (wn + j * 16 + fr) * 40 + fg * 8);
    #pragma unroll
    for (int i = 0; i < 4; ++i)
      #pragma unroll
      for (int j = 0; j < NJ; ++j)
        acc[i][j] = __builtin_amdgcn_mfma_f32_16x16x32_bf16(af[i], bfr[j], acc[i][j], 0, 0, 0);
  }

  #pragma unroll
  for (int j = 0; j < NJ; ++j) {
    int col = n0 + wn + j * 16 + fr;
    float bv = 0.f;
    if (MODE == MODE_Y_RES) bv = bias[col];
    if (MODE == MODE_GLU)   bv = bias[(col >> 1) + ((col & 1) << 9)];
    float scj = 0.f, sfj = 0.f;
    if (RESN == 2) {
      float mean = nsum[bIdx * 256 + col] * inv1024;
      float var = nsq[bIdx * 256 + col] * inv1024 - mean * mean;
      float rstd = rsqrtf(var + 1e-5f);
      scj = rstd * ngam[col];
      sfj = nbet[col] - mean * scj;
    }
    float sj = 0.f, qj = 0.f;
    #pragma unroll
    for (int i = 0; i < 4; ++i) {
      #pragma unroll
      for (int r = 0; r < 4; ++r) {
        int row = m0 + wm + i * 16 + fg * 4 + r;
        float v = acc[i][j][r] + bv;
        if (MODE == MODE_QKV) {
          int which = col >> 8, h = (col >> 4) & 15, d = col & 15;
          int b = row >> 10, ns = row & 1023;
          outB[(size_t)which * 4194304 + (((size_t)(b * 16 + h) * 1024 + ns) * 16 + d)] = f2bf(v);
        } else if (MODE == MODE_Y_RES) {
          size_t idx = (size_t)row * N + col;
          float rv = bf2f(resp[idx]);
          if (RESN == 2) rv = rv * scj + sfj;
          float y = v + rv;
          outB[idx] = f2bf(y);
          if (STATS) { sj += y; qj += y * y; }
        } else { // MODE_GLU
          float partner = __shfl_xor(v, 1);
          if ((fr & 1) == 0) {
            float g = partner / (1.f + __expf(-partner));  // silu(gate)
            outB[(size_t)row * 512 + (col >> 1)] = f2bf(g * v);
          }
        }
      }
    }
    if (STATS) {
      sj += __shfl_xor(sj, 16); sj += __shfl_xor(sj, 32);
      qj += __shfl_xor(qj, 16); qj += __shfl_xor(qj, 32);
      if (fg == 0) {
        atomicAdd(&ssum[bIdx * 256 + col], sj);
        atomicAdd(&ssq[bIdx * 256 + col], qj);
      }
    }
  }
}

// ---------------------------------------------------------------------------
// Attention v3 (unchanged from r6): K-streaming flash, no max-tracking,
// 128-key chunks, double-buffered LDS with register prefetch, XCD swizzle.
// ---------------------------------------------------------------------------
#define SCALE_L2 0.360673760222241f   /* (1/sqrt(16)) * log2(e) */

__launch_bounds__(512, 4)
__global__ void attn_kernel(const u16* __restrict__ Q, const u16* __restrict__ Kg,
                            const u16* __restrict__ Vg, u16* __restrict__ attn)
{
  __shared__ u16 Ks[2][128 * 24];   // [buf][pos][d] d padded 16->24
  __shared__ u16 Vt[2][16 * 136];   // [buf][d][key] key padded 128->136
  __shared__ u16 Pb[8][16 * 40];    // per-wave P [qrow][key-in-32 + pad]
  const int t = threadIdx.x;
  const int bh = blockIdx.x & 255;
  const int qg = blockIdx.x >> 8;
  const int b = bh >> 4, h = bh & 15;
  const size_t base = (size_t)bh * 16384;
  const int w = t >> 6, lane = t & 63;
  const int fr = lane & 15, fg = lane >> 4;
  u16* Pw = Pb[w];
  const int q0 = qg * 128 + w * 16;
  const f32x4 zero4 = (f32x4){0.f, 0.f, 0.f, 0.f};

  const int su = (t & 255) >> 1;
  const int sh = t & 1;
  const bool isK = t < 256;
  const int blk = su >> 5, ii = su & 31;
  const int kpos = blk * 32 + ((ii & 1) ? 16 + (ii >> 1) : (ii >> 1));

  bf16x8 qf = {};
  if (fg < 2) {
    union { u16 u[8]; uint4 v; bf16x8 f; } qt;
    qt.v = *(const uint4*)(Q + base + (size_t)(q0 + fr) * 16 + fg * 8);
    #pragma unroll
    for (int j = 0; j < 8; ++j) qt.u[j] = f2bf(bf2f(qt.u[j]) * SCALE_L2);
    qf = qt.f;
  }

  {
    uint4 pre = isK ? *(const uint4*)(Kg + base + (size_t)su * 16 + sh * 8)
                    : *(const uint4*)(Vg + base + (size_t)su * 16 + sh * 8);
    if (isK) {
      *(uint4*)(&Ks[0][kpos * 24 + sh * 8]) = pre;
    } else {
      union { u16 u[8]; uint4 v; } pk; pk.v = pre;
      #pragma unroll
      for (int j = 0; j < 8; ++j) Vt[0][(sh * 8 + j) * 136 + su] = pk.u[j];
    }
  }
  __syncthreads();

  f32x4 acco = zero4;
  float lsum[4] = {0.f, 0.f, 0.f, 0.f};

  for (int c = 0; c < 8; ++c) {
    uint4 nxt;
    if (c < 7) {
      const size_t off = base + (size_t)((c + 1) * 128 + su) * 16 + sh * 8;
      nxt = isK ? *(const uint4*)(Kg + off) : *(const uint4*)(Vg + off);
    }
    const u16* KsC = Ks[c & 1];
    const u16* VtC = Vt[c & 1];
    #pragma unroll
    for (int sub = 0; sub < 4; ++sub) {
      const int kb = sub * 32;
      bf16x8 kf0 = {}, kf1 = {};
      if (fg < 2) {
        kf0 = *(const bf16x8*)(KsC + (kb + fr) * 24 + fg * 8);
        kf1 = *(const bf16x8*)(KsC + (kb + 16 + fr) * 24 + fg * 8);
      }
      f32x4 s0 = __builtin_amdgcn_mfma_f32_16x16x32_bf16(qf, kf0, zero4, 0, 0, 0);
      f32x4 s1 = __builtin_amdgcn_mfma_f32_16x16x32_bf16(qf, kf1, zero4, 0, 0, 0);
      #pragma unroll
      for (int r = 0; r < 4; ++r) {
        float p0 = fexp2(s0[r]);
        float p1 = fexp2(s1[r]);
        lsum[r] += p0 + p1;
        *(unsigned*)(Pw + (fg * 4 + r) * 40 + 2 * fr) =
            __builtin_amdgcn_perm(__float_as_uint(p1), __float_as_uint(p0), 0x07060302u);
      }
      __asm__ volatile("s_waitcnt lgkmcnt(0)" ::: "memory");
      bf16x8 pf = *(const bf16x8*)(Pw + fr * 40 + fg * 8);
      bf16x8 vf = *(const bf16x8*)(VtC + fr * 136 + kb + fg * 8);
      __asm__ volatile("" ::: "memory");
      acco = __builtin_amdgcn_mfma_f32_16x16x32_bf16(pf, vf, acco, 0, 0, 0);
    }
    if (c < 7) {
      if (isK) {
        *(uint4*)(&Ks[(c + 1) & 1][kpos * 24 + sh * 8]) = nxt;
      } else {
        union { u16 u[8]; uint4 v; } pk; pk.v = nxt;
        #pragma unroll
        for (int j = 0; j < 8; ++j) Vt[(c + 1) & 1][(sh * 8 + j) * 136 + su] = pk.u[j];
      }
    }
    __syncthreads();
  }

  #pragma unroll
  for (int r = 0; r < 4; ++r) {
    float l = lsum[r];
    l += __shfl_xor(l, 1); l += __shfl_xor(l, 2);
    l += __shfl_xor(l, 4); l += __shfl_xor(l, 8);
    int row = q0 + fg * 4 + r;
    attn[((size_t)(b * 1024 + row)) * 256 + h * 16 + fr] = f2bf(acco[r] / l);
  }
}

// ---------------------------------------------------------------------------
// Final instance-norm apply -> fp32 output.
// ---------------------------------------------------------------------------
__global__ void apply_kernel(const u16* __restrict__ y, const float* __restrict__ ssum,
                             const float* __restrict__ ssq, const float* __restrict__ gamma,
                             const float* __restrict__ beta, float* __restrict__ outp)
{
  int idx = (blockIdx.x * 256 + threadIdx.x) * 4;
  int e = idx & 255;
  int b = idx >> 18;
  union { u16 u[4]; uint2 v; } in;
  in.v = *(const uint2*)(y + idx);
  float ov[4];
  const float inv = 1.f / 1024.f;
  #pragma unroll
  for (int j = 0; j < 4; ++j) {
    int ej = e + j;
    float mean = ssum[b * 256 + ej] * inv;
    float var = ssq[b * 256 + ej] * inv - mean * mean;
    float rstd = rsqrtf(var + 1e-5f);
    ov[j] = (bf2f(in.u[j]) - mean) * rstd * gamma[ej] + beta[ej];
  }
  *(float4*)(outp + idx) = make_float4(ov[0], ov[1], ov[2], ov[3]);
}

// ---------------------------------------------------------------------------
extern "C" void kernel_launch(void* const* d_in, const int* in_sizes, int n_in,
                              void* d_out, int out_size, void* d_ws, size_t ws_size,
                              hipStream_t stream)
{
  const float* x      = (const float*)d_in[0];
  const float* Wq     = (const float*)d_in[1];
  const float* Wk     = (const float*)d_in[2];
  const float* Wv     = (const float*)d_in[3];
  const float* Wo     = (const float*)d_in[4];
  const float* bo     = (const float*)d_in[5];
  const float* gamma1 = (const float*)d_in[6];
  const float* beta1  = (const float*)d_in[7];
  const float* gamma2 = (const float*)d_in[8];
  const float* beta2  = (const float*)d_in[9];
  const float* W1     = (const float*)d_in[10];
  const float* b1     = (const float*)d_in[11];
  const float* W2     = (const float*)d_in[12];
  const float* b2     = (const float*)d_in[13];

  // Workspace (49.3 MB peak, lifetime-aliased):
  //  0         WT 1.25MB + SS 64K                       [permanent]
  //  1376256   xb bf16 8MB     [prep -> qkv A, wo residual]
  //  9764864   Qb bf16 24MB    [qkv -> attn]
  //  34930688  ATTN bf16 8MB   [attn -> wo]             ends 43319296 (peak 49.3MB w/ Y2)
  //  9764864   Y1 bf16 8MB     [wo -> glu A(norm), w2 res(norm)]  (alias Qb.Q, dead)
  //  18153472  G bf16 16MB     [glu -> w2]              (alias Qb.K/V, dead)
  //  34930688  Y2 bf16 8MB     [w2 -> apply2]           (alias ATTN, dead)
  char* ws = (char*)d_ws;
  u16*   WQKVT = (u16*)(ws + 0);
  u16*   WOT   = (u16*)(ws + 393216);
  u16*   W1T   = (u16*)(ws + 524288);
  u16*   W2T   = (u16*)(ws + 1048576);
  float* SS    = (float*)(ws + 1310720);
  float* SSUM1 = SS;
  float* SSQ1  = SS + 4096;
  float* SSUM2 = SS + 8192;
  float* SSQ2  = SS + 12288;
  u16*   xb    = (u16*)(ws + 1376256);
  u16*   Qb    = (u16*)(ws + 9764864);
  u16*   ATTN  = (u16*)(ws + 34930688);
  u16*   Y1    = (u16*)(ws + 9764864);
  u16*   G     = (u16*)(ws + 18153472);
  u16*   Y2    = (u16*)(ws + 34930688);

  prep_kernel<<<2688, 256, 0, stream>>>(x, xb, Wq, Wk, Wv, Wo, W1, W2,
                                        WQKVT, WOT, W1T, W2T, SS);

  // QKV projection: (16384x256) @ (256x768) -> scatter bf16 [b][h][n][d]
  gemm_kernel<MODE_QKV, 128, 0, 0, 0><<<dim3(128, 6), 256, 0, stream>>>(
      xb, WQKVT, 16384, 768, 256, nullptr, nullptr, Qb,
      nullptr, nullptr, nullptr, nullptr, nullptr, nullptr);

  attn_kernel<<<2048, 512, 0, stream>>>(Qb, Qb + 4194304, Qb + 8388608, ATTN);

  // Y1 = attn @ Wo + bo + x  (res = xb bf16; fused stats -> SSUM1/SSQ1)
  gemm_kernel<MODE_Y_RES, 64, 1, 1, 0><<<dim3(128, 4), 256, 0, stream>>>(
      ATTN, WOT, 16384, 256, 256, bo, xb, Y1,
      SSUM1, SSQ1, nullptr, nullptr, nullptr, nullptr);

  // G = silu(gate)*x_part of (norm1(Y1) @ W1interleaved + b1); norm fused in staging
  gemm_kernel<MODE_GLU, 128, 0, 0, 1><<<dim3(128, 8), 256, 0, stream>>>(
      Y1, W1T, 16384, 1024, 256, b1, nullptr, G,
      nullptr, nullptr, SSUM1, SSQ1, gamma1, beta1);

  // Y2 = G @ W2 + b2 + norm1(Y1)  (res-norm fused; stats -> SSUM2/SSQ2)
  gemm_kernel<MODE_Y_RES, 64, 2, 1, 0><<<dim3(128, 4), 256, 0, stream>>>(
      G, W2T, 16384, 256, 512, b2, Y1, Y2,
      SSUM2, SSQ2, SSUM1, SSQ1, gamma1, beta1);

  apply_kernel<<<4096, 256, 0, stream>>>(Y2, SSUM2, SSQ2, gamma2, beta2, (float*)d_out);
}